// Round 4
// baseline (419.590 us; speedup 1.0000x reference)
//
#include <hip/hip_runtime.h>

#define HID 52
#define HID2 104
#define P1_CHUNK 4096
#define NBIN_MAX 512      // bins of 256 nodes; N <= 131072
#define HSTRIDE 136

typedef unsigned short ushort_t;
typedef unsigned int uint_t;
typedef short bf16x8 __attribute__((ext_vector_type(8)));
typedef float f32x4 __attribute__((ext_vector_type(4)));
typedef float f32x2 __attribute__((ext_vector_type(2)));

__device__ __forceinline__ ushort_t f2bf(float f) {
    union { float f; uint_t u; } c; c.f = f;
    uint_t u = c.u + 0x7FFFu + ((c.u >> 16) & 1u);   // RNE
    return (ushort_t)(u >> 16);
}
__device__ __forceinline__ float bflo(uint_t u) {
    union { uint_t u; float f; } c; c.u = u << 16; return c.f;
}
__device__ __forceinline__ float bfhi(uint_t u) {
    union { uint_t u; float f; } c; c.u = u & 0xFFFF0000u; return c.f;
}
// raw pair: (a,b) reinterpreted as two f32 -> the two ODD (hi) channels, noisy-mantissa
__device__ __forceinline__ f32x2 rawpair(uint_t a, uint_t b) {
    union { uint_t u; float f; } ca, cb; ca.u = a; cb.u = b;
    return (f32x2){ca.f, cb.f};
}
// shifted pair: (a<<16, b<<16) -> the two EVEN (lo) channels, exact
__device__ __forceinline__ f32x2 shlpair(uint_t a, uint_t b) {
    union { uint_t u; float f; } ca, cb; ca.u = a << 16; cb.u = b << 16;
    return (f32x2){ca.f, cb.f};
}
// in-place packed add: a += b in ONE VOP3P instr ("+v" ties dst=src0)
__device__ __forceinline__ void pkacc(f32x2& a, f32x2 b) {
    asm("v_pk_add_f32 %0, %0, %1" : "+v"(a) : "v"(b));
}
// cross-lane xor within 32-lane halves via ds_swizzle BitMode (imm = (xor<<10)|0x1F)
template<int IMM>
__device__ __forceinline__ f32x2 swz2(f32x2 v) {
    union { float f; int i; } a, b; a.f = v.x; b.f = v.y;
    int ra = __builtin_amdgcn_ds_swizzle(a.i, IMM);
    int rb = __builtin_amdgcn_ds_swizzle(b.i, IMM);
    union { int i; float f; } c, d; c.i = ra; d.i = rb;
    return (f32x2){c.f, d.f};
}

// ---------- fused setup: conv_x + zero pad rows + conv_w + bhist ----------
// ghist/gcnt are pre-zeroed by a hipMemsetAsync before this kernel.
__global__ __launch_bounds__(256) void setup_kernel(const float* __restrict__ x,
                                                    const float* __restrict__ w1,
                                                    const float* __restrict__ w2,
                                                    const float* __restrict__ lin_w,
                                                    const int* __restrict__ dst,
                                                    ushort_t* __restrict__ xb,
                                                    ushort_t* __restrict__ h1b,
                                                    ushort_t* __restrict__ h2b,
                                                    ushort_t* __restrict__ w1f,
                                                    ushort_t* __restrict__ w2f,
                                                    ushort_t* __restrict__ linf,
                                                    int* __restrict__ ghist,
                                                    int n, int E, int nxblk) {
    __shared__ int lh[NBIN_MAX];
    int blk = blockIdx.x;
    int tid = threadIdx.x;
    if (blk < nxblk) {
        int t = blk * 256 + tid;
        if (t >= n * 16) return;
        int node = t >> 4, pp = t & 15;
        int c0 = pp * 4;
        ushort_t o[4];
#pragma unroll
        for (int j = 0; j < 4; j++) {
            int c = c0 + j;
            o[j] = (c < HID) ? f2bf(x[(size_t)node * HID + c]) : 0;
        }
        uint_t u0 = (uint_t)o[0] | ((uint_t)o[1] << 16);
        uint_t u1 = (uint_t)o[2] | ((uint_t)o[3] << 16);
        *(uint2*)(xb + (size_t)node * 64 + c0) = make_uint2(u0, u1);
        return;
    }
    if (blk == nxblk) {
        ushort_t* arr = (tid < 64) ? xb : (tid < 128) ? h1b : h2b;  // 192-255 dup h2b: benign
        arr[(size_t)n * 64 + (tid & 63)] = 0;
        return;
    }
    if (blk < nxblk + 32) {
        int gid = (blk - nxblk - 1) * 4 + (tid >> 6);
        int lane = tid & 63;
        if (gid >= 122) return;
        int m = lane & 15, q = lane >> 4;
        ushort_t o[8];
        ushort_t* dstp;
        if (gid < 42) {
            int l = gid / 14, r = gid % 14, ct = r >> 1, ks = r & 1;
            int nn = ct * 16 + m;
#pragma unroll
            for (int j = 0; j < 8; j++) {
                int k = ks * 32 + q * 8 + j;
                o[j] = (k < HID && nn < HID2) ? f2bf(w1[((size_t)l * HID + k) * HID2 + nn]) : 0;
            }
            dstp = w1f + ((size_t)(l * 14 + ct * 2 + ks) * 64 + lane) * 8;
        } else if (gid < 90) {
            int g2 = gid - 42, l = g2 / 16, r = g2 % 16, ct = r >> 2, ks = r & 3;
            int nn = ct * 16 + m;
#pragma unroll
            for (int j = 0; j < 8; j++) {
                int k = ks * 32 + q * 8 + j;
                o[j] = (k < HID2 && nn < HID) ? f2bf(w2[((size_t)l * HID2 + k) * HID + nn]) : 0;
            }
            dstp = w2f + ((size_t)(l * 16 + ct * 4 + ks) * 64 + lane) * 8;
        } else {
            int g2 = gid - 90, ct = g2 >> 3, ks = g2 & 7;
            int nn = ct * 16 + m;
#pragma unroll
            for (int j = 0; j < 8; j++) {
                int kg = ks * 32 + q * 8 + j;
                int seg = kg >> 6, kk = kg & 63;
                o[j] = (kk < HID && nn < HID) ? f2bf(lin_w[((size_t)seg * HID + kk) * HID + nn]) : 0;
            }
            dstp = linf + ((size_t)(ct * 8 + ks) * 64 + lane) * 8;
        }
        uint4 u;
        u.x = (uint_t)o[0] | ((uint_t)o[1] << 16);
        u.y = (uint_t)o[2] | ((uint_t)o[3] << 16);
        u.z = (uint_t)o[4] | ((uint_t)o[5] << 16);
        u.w = (uint_t)o[6] | ((uint_t)o[7] << 16);
        *(uint4*)dstp = u;
        return;
    }
    // ---- bhist section ----
    int eblk = blk - nxblk - 32;
    lh[tid] = 0; lh[tid + 256] = 0;
    __syncthreads();
    int base = eblk * P1_CHUNK;
    int cend = min(P1_CHUNK, E - base);
    for (int i = tid; i < cend; i += 256) atomicAdd(&lh[dst[base + i] >> 8], 1);
    __syncthreads();
    int cc = lh[tid];       if (cc) atomicAdd(&ghist[tid], cc);
    cc = lh[tid + 256];     if (cc) atomicAdd(&ghist[tid + 256], cc);
}

// ---------- binstart: one-block exclusive scan over the 512-bin histogram ----------
__global__ __launch_bounds__(256) void binscan_kernel(const int* __restrict__ ghist,
                                                      int* __restrict__ binstart) {
    __shared__ int ps[256];
    int tid = threadIdx.x;
    int g0 = ghist[2 * tid], g1 = ghist[2 * tid + 1];
    int pair = g0 + g1;
    ps[tid] = pair;
    __syncthreads();
    for (int off = 1; off < 256; off <<= 1) {
        int t = (tid >= off) ? ps[tid - off] : 0;
        __syncthreads();
        ps[tid] += t;
        __syncthreads();
    }
    int ex = ps[tid] - pair;
    binstart[2 * tid] = ex;
    binstart[2 * tid + 1] = ex + g0;
}

// ---------- pass 1: DIRECT bin-partition (no LDS staging) ----------
// r3 lesson: the stage[]/sbin[] pipeline (6 LDS ops/edge, 4 barriers) was the cost,
// not occupancy. Direct form: 2 LDS ops/edge, 2 barriers, 4KB LDS.
// Writes land in ~8-edge consecutive runs per bin per block (pass2 already
// sustains this exact scattered-cursor write pattern without showing in top-5).
__global__ __launch_bounds__(256) void pass1_kernel(const int* __restrict__ src,
                                                    const int* __restrict__ dst,
                                                    const int* __restrict__ binstart,
                                                    int* __restrict__ gcnt,
                                                    uint_t* __restrict__ packed, int E) {
    __shared__ int cnt[NBIN_MAX];
    __shared__ int cur[NBIN_MAX];
    int tid = threadIdx.x;
    int b0 = 2 * tid, b1 = 2 * tid + 1;
    cnt[b0] = 0; cnt[b1] = 0;
    __syncthreads();
    int base = blockIdx.x * P1_CHUNK;
    int cend = min(P1_CHUNK, E - base);
    for (int i = tid; i < cend; i += 256) atomicAdd(&cnt[dst[base + i] >> 8], 1);
    __syncthreads();
    int c0 = cnt[b0], c1 = cnt[b1];
    cur[b0] = c0 ? (binstart[b0] + atomicAdd(&gcnt[b0], c0)) : 0;
    cur[b1] = c1 ? (binstart[b1] + atomicAdd(&gcnt[b1], c1)) : 0;
    __syncthreads();
    for (int i = tid; i < cend; i += 256) {
        int d = dst[base + i];
        int s = src[base + i];
        int b = d >> 8;
        int pos = atomicAdd(&cur[b], 1);
        packed[pos] = ((uint_t)s << 8) | (uint_t)(d & 255);
    }
}

// ---------- pass 2: per-bin counting sort (plain node key), padded runs ----------
__global__ __launch_bounds__(256) void pass2_kernel(const uint_t* __restrict__ packed,
                                                    const int* __restrict__ ghist,
                                                    const int* __restrict__ binstart,
                                                    int* __restrict__ srcsorted,
                                                    int* __restrict__ nrs,
                                                    int* __restrict__ ndeg, int N) {
    __shared__ int ps[256];
    __shared__ int hist[256];
    __shared__ int curs[256];
    int b = blockIdx.x;
    int tid = threadIdx.x;
    hist[tid] = 0;
    __syncthreads();
    int beg = binstart[b];
    int end = beg + ghist[b];
    int obase = beg + b * 4096;
    for (int i = beg + tid; i < end; i += 256) atomicAdd(&hist[packed[i] & 255u], 1);
    __syncthreads();
    int v = hist[tid];
    int pv = (v + 15) & ~15;
    ps[tid] = pv;
    __syncthreads();
    for (int off = 1; off < 256; off <<= 1) {
        int t = (tid >= off) ? ps[tid - off] : 0;
        __syncthreads();
        ps[tid] += t;
        __syncthreads();
    }
    int start = obase + ps[tid] - pv;
    int node = b * 256 + tid;
    if (node < N) { nrs[node] = start; ndeg[node] = pv; }
    curs[tid] = start;
    __syncthreads();
    for (int i = beg + tid; i < end; i += 256) {
        uint_t p = packed[i];
        int pos = atomicAdd(&curs[p & 255u], 1);
        srcsorted[pos] = (int)(p >> 8);
    }
    __syncthreads();
    for (int i = start + v; i < start + pv; i++) srcsorted[i] = N;   // zero-row pads
}

// ---------- aggregation: 2 nodes/wave (lane halves), 8 row-gathers in flight ----------
// At the ~3.45 TB/s L2-miss wall for this gather pattern (r2 A/B: 2x concurrency -> +5% BW).
__global__ __launch_bounds__(256) void agg_kernel(const ushort_t* __restrict__ hb,
                                                  const int* __restrict__ nrs,
                                                  const int* __restrict__ ndeg,
                                                  const int* __restrict__ srcsorted,
                                                  const float* __restrict__ eps,
                                                  ushort_t* __restrict__ zb, int n) {
    int wpair = (blockIdx.x * blockDim.x + threadIdx.x) >> 6;
    int lane = threadIdx.x & 63;
    int half = lane >> 5;
    int wid = wpair * 2 + half;
    bool valid = (wid < n);
    int node = valid ? wid : (n - 1);
    int hl = lane & 31;
    int g = hl >> 3;                         // 0..3 group within half
    int sub = lane & 7;
    int beg = nrs[node];
    int total = valid ? ndeg[node] : 0;      // multiple of 16
    const char* hc = (const char*)hb;        // uniform base (SGPR)
    const char* sp = (const char*)srcsorted; // uniform base (SGPR)
    unsigned lbB = (unsigned)sub * 16u;      // byte offset of lane's 16B row segment
    unsigned bo = (unsigned)(beg + g) * 4u;  // byte offset of lane's index stream

    // O*=(odd ch, noisy-hi raw) E*=(even ch exact); A: even rows, B: odd rows
    f32x2 AO0 = {0,0}, AO1 = {0,0}, AE0 = {0,0}, AE1 = {0,0};
    f32x2 BO0 = {0,0}, BO1 = {0,0}, BE0 = {0,0}, BE1 = {0,0};
    if (total > 0) {
        int f0 = *(const int*)(sp + bo);
        int f1 = *(const int*)(sp + bo + 16);
        int f2 = *(const int*)(sp + bo + 32);
        int f3 = *(const int*)(sp + bo + 48);
        int f4 = *(const int*)(sp + bo + 64);
        int f5 = *(const int*)(sp + bo + 80);
        int f6 = *(const int*)(sp + bo + 96);
        int f7 = *(const int*)(sp + bo + 112);
        for (int b = 0; b < total; b += 32) {
            bool ok = (b + 16) < total;
            int e0 = f0, e1 = f1, e2 = f2, e3 = f3;
            int e4 = ok ? f4 : n, e5 = ok ? f5 : n;
            int e6 = ok ? f6 : n, e7 = ok ? f7 : n;
            f0 = *(const int*)(sp + bo + 128);
            f1 = *(const int*)(sp + bo + 144);
            f2 = *(const int*)(sp + bo + 160);
            f3 = *(const int*)(sp + bo + 176);
            f4 = *(const int*)(sp + bo + 192);
            f5 = *(const int*)(sp + bo + 208);
            f6 = *(const int*)(sp + bo + 224);
            f7 = *(const int*)(sp + bo + 240);
            bo += 128;
            uint4 v0 = *(const uint4*)(hc + (((unsigned)e0 << 7) + lbB));
            uint4 v1 = *(const uint4*)(hc + (((unsigned)e1 << 7) + lbB));
            uint4 v2 = *(const uint4*)(hc + (((unsigned)e2 << 7) + lbB));
            uint4 v3 = *(const uint4*)(hc + (((unsigned)e3 << 7) + lbB));
            uint4 v4 = *(const uint4*)(hc + (((unsigned)e4 << 7) + lbB));
            uint4 v5 = *(const uint4*)(hc + (((unsigned)e5 << 7) + lbB));
            uint4 v6 = *(const uint4*)(hc + (((unsigned)e6 << 7) + lbB));
            uint4 v7 = *(const uint4*)(hc + (((unsigned)e7 << 7) + lbB));
            pkacc(AO0, rawpair(v0.x, v0.y)); pkacc(AO1, rawpair(v0.z, v0.w));
            pkacc(AE0, shlpair(v0.x, v0.y)); pkacc(AE1, shlpair(v0.z, v0.w));
            pkacc(BO0, rawpair(v1.x, v1.y)); pkacc(BO1, rawpair(v1.z, v1.w));
            pkacc(BE0, shlpair(v1.x, v1.y)); pkacc(BE1, shlpair(v1.z, v1.w));
            pkacc(AO0, rawpair(v2.x, v2.y)); pkacc(AO1, rawpair(v2.z, v2.w));
            pkacc(AE0, shlpair(v2.x, v2.y)); pkacc(AE1, shlpair(v2.z, v2.w));
            pkacc(BO0, rawpair(v3.x, v3.y)); pkacc(BO1, rawpair(v3.z, v3.w));
            pkacc(BE0, shlpair(v3.x, v3.y)); pkacc(BE1, shlpair(v3.z, v3.w));
            pkacc(AO0, rawpair(v4.x, v4.y)); pkacc(AO1, rawpair(v4.z, v4.w));
            pkacc(AE0, shlpair(v4.x, v4.y)); pkacc(AE1, shlpair(v4.z, v4.w));
            pkacc(BO0, rawpair(v5.x, v5.y)); pkacc(BO1, rawpair(v5.z, v5.w));
            pkacc(BE0, shlpair(v5.x, v5.y)); pkacc(BE1, shlpair(v5.z, v5.w));
            pkacc(AO0, rawpair(v6.x, v6.y)); pkacc(AO1, rawpair(v6.z, v6.w));
            pkacc(AE0, shlpair(v6.x, v6.y)); pkacc(AE1, shlpair(v6.z, v6.w));
            pkacc(BO0, rawpair(v7.x, v7.y)); pkacc(BO1, rawpair(v7.z, v7.w));
            pkacc(BE0, shlpair(v7.x, v7.y)); pkacc(BE1, shlpair(v7.z, v7.w));
        }
    }
    pkacc(AO0, BO0); pkacc(AO1, BO1);
    pkacc(AE0, BE0); pkacc(AE1, BE1);
    // stage 1: xor-8 (sum group pairs), stage 2: xor-16 (sum quads) — within halves
    pkacc(AO0, swz2<0x201F>(AO0)); pkacc(AO1, swz2<0x201F>(AO1));
    pkacc(AE0, swz2<0x201F>(AE0)); pkacc(AE1, swz2<0x201F>(AE1));
    pkacc(AO0, swz2<0x401F>(AO0)); pkacc(AO1, swz2<0x401F>(AO1));
    pkacc(AE0, swz2<0x401F>(AE0)); pkacc(AE1, swz2<0x401F>(AE1));
    if (hl < 8 && valid) {
        // channel map in this lane's 8-ch sub-block:
        //   AE0=(c0,c2) AO0=(c1,c3) AE1=(c4,c6) AO1=(c5,c7)
        float sc = 1.0f + eps[0];
        uint4 sv = *(const uint4*)(hb + (size_t)wid * 64 + hl * 8);
        float o0 = fmaf(sc, bflo(sv.x), AE0.x), o1 = fmaf(sc, bfhi(sv.x), AO0.x);
        float o2 = fmaf(sc, bflo(sv.y), AE0.y), o3 = fmaf(sc, bfhi(sv.y), AO0.y);
        float o4 = fmaf(sc, bflo(sv.z), AE1.x), o5 = fmaf(sc, bfhi(sv.z), AO1.x);
        float o6 = fmaf(sc, bflo(sv.w), AE1.y), o7 = fmaf(sc, bfhi(sv.w), AO1.y);
        uint4 u;
        u.x = (uint_t)f2bf(o0) | ((uint_t)f2bf(o1) << 16);
        u.y = (uint_t)f2bf(o2) | ((uint_t)f2bf(o3) << 16);
        u.z = (uint_t)f2bf(o4) | ((uint_t)f2bf(o5) << 16);
        u.w = (uint_t)f2bf(o6) | ((uint_t)f2bf(o7) << 16);
        *(uint4*)(zb + (size_t)wid * 64 + hl * 8) = u;
    }
}

// ---------- MFMA fused 2-layer MLP; LAST=1 also fuses the final concat linear ----------
template<int LAST>
__global__ __launch_bounds__(256) void mlp_kernel(const ushort_t* __restrict__ zb,
                                                  const ushort_t* __restrict__ w1f,
                                                  const float* __restrict__ b1,
                                                  const ushort_t* __restrict__ w2f,
                                                  const float* __restrict__ b2,
                                                  ushort_t* __restrict__ hbout,
                                                  const ushort_t* __restrict__ xb,
                                                  const ushort_t* __restrict__ h1b,
                                                  const ushort_t* __restrict__ h2b,
                                                  const ushort_t* __restrict__ linf,
                                                  const float* __restrict__ lin_b,
                                                  float* __restrict__ out, int n) {
    __shared__ ushort_t hid[64 * HSTRIDE];
    __shared__ ushort_t h3t[LAST ? 64 * 68 : 1];
    int tid = threadIdx.x;
    int w = tid >> 6, lane = tid & 63, m = lane & 15, q = lane >> 4;
    for (int i = tid; i < 64 * 32; i += 256) {
        int r = i >> 5, c = HID2 + (i & 31);
        hid[r * HSTRIDE + c] = 0;
    }
    __syncthreads();

    int nb = blockIdx.x * 64 + w * 16;
    f32x4 acc1[7];
#pragma unroll
    for (int ct = 0; ct < 7; ct++) {
        int col = ct * 16 + m;
        float bv = (col < HID2) ? b1[col] : 0.f;
        acc1[ct] = (f32x4){bv, bv, bv, bv};
    }
    int anode = min(nb + m, n - 1);
#pragma unroll
    for (int ks = 0; ks < 2; ks++) {
        bf16x8 a = *(const bf16x8*)(zb + (size_t)anode * 64 + ks * 32 + q * 8);
#pragma unroll
        for (int ct = 0; ct < 7; ct++) {
            bf16x8 b = *(const bf16x8*)(w1f + ((size_t)(ct * 2 + ks) * 64 + lane) * 8);
            acc1[ct] = __builtin_amdgcn_mfma_f32_16x16x32_bf16(a, b, acc1[ct], 0, 0, 0);
        }
    }
#pragma unroll
    for (int ct = 0; ct < 7; ct++) {
#pragma unroll
        for (int r = 0; r < 4; r++) {
            float v = fmaxf(acc1[ct][r], 0.f);
            int row = w * 16 + q * 4 + r;
            hid[row * HSTRIDE + ct * 16 + m] = f2bf(v);
        }
    }
    f32x4 acc2[4];
#pragma unroll
    for (int ct = 0; ct < 4; ct++) {
        int col = ct * 16 + m;
        float bv = (col < HID) ? b2[col] : 0.f;
        acc2[ct] = (f32x4){bv, bv, bv, bv};
    }
#pragma unroll
    for (int ks = 0; ks < 4; ks++) {
        bf16x8 a = *(const bf16x8*)&hid[(w * 16 + m) * HSTRIDE + ks * 32 + q * 8];
#pragma unroll
        for (int ct = 0; ct < 4; ct++) {
            bf16x8 b = *(const bf16x8*)(w2f + ((size_t)(ct * 4 + ks) * 64 + lane) * 8);
            acc2[ct] = __builtin_amdgcn_mfma_f32_16x16x32_bf16(a, b, acc2[ct], 0, 0, 0);
        }
    }

    if (!LAST) {
#pragma unroll
        for (int ct = 0; ct < 4; ct++) {
#pragma unroll
            for (int r = 0; r < 4; r++) {
                int node = nb + q * 4 + r;
                if (node < n) {
                    float v = fmaxf(acc2[ct][r], 0.f);
                    hbout[(size_t)node * 64 + ct * 16 + m] = f2bf(v);
                }
            }
        }
    } else {
        // h3 (C-layout) -> LDS tile; wave-private rows, no barrier needed
#pragma unroll
        for (int ct = 0; ct < 4; ct++) {
#pragma unroll
            for (int r = 0; r < 4; r++) {
                float v = fmaxf(acc2[ct][r], 0.f);
                h3t[(w * 16 + q * 4 + r) * 68 + ct * 16 + m] = f2bf(v);
            }
        }
        // final: [16 x 256] @ [256 x 64]; segs x,h1,h2 from global, h3 from LDS
        f32x4 accF[4];
#pragma unroll
        for (int ct = 0; ct < 4; ct++) {
            int col = ct * 16 + m;
            float bv = (col < HID) ? lin_b[col] : 0.f;
            accF[ct] = (f32x4){bv, bv, bv, bv};
        }
        const ushort_t* segs[3] = {xb, h1b, h2b};
#pragma unroll
        for (int ks = 0; ks < 8; ks++) {
            bf16x8 a;
            if (ks < 6) {
                const ushort_t* p = segs[ks >> 1];
                a = *(const bf16x8*)(p + (size_t)anode * 64 + (ks & 1) * 32 + q * 8);
            } else {
                a = *(const bf16x8*)&h3t[(w * 16 + m) * 68 + (ks & 1) * 32 + q * 8];
            }
#pragma unroll
            for (int ct = 0; ct < 4; ct++) {
                bf16x8 b = *(const bf16x8*)(linf + ((size_t)(ct * 8 + ks) * 64 + lane) * 8);
                accF[ct] = __builtin_amdgcn_mfma_f32_16x16x32_bf16(a, b, accF[ct], 0, 0, 0);
            }
        }
#pragma unroll
        for (int ct = 0; ct < 4; ct++) {
            int col = ct * 16 + m;
            if (col < HID) {
#pragma unroll
                for (int r = 0; r < 4; r++) {
                    int node = nb + q * 4 + r;
                    if (node < n)
                        out[(size_t)node * HID + col] = accF[ct][r];
                }
            }
        }
    }
}

extern "C" void kernel_launch(void* const* d_in, const int* in_sizes, int n_in,
                              void* d_out, int out_size, void* d_ws, size_t ws_size,
                              hipStream_t stream) {
    const float* x     = (const float*)d_in[0];
    const int*   ei    = (const int*)d_in[1];
    const float* w1    = (const float*)d_in[2];
    const float* b1    = (const float*)d_in[3];
    const float* w2    = (const float*)d_in[4];
    const float* b2    = (const float*)d_in[5];
    const float* eps   = (const float*)d_in[6];
    const float* lin_w = (const float*)d_in[7];
    const float* lin_b = (const float*)d_in[8];
    float* out = (float*)d_out;

    const int N = in_sizes[0] / HID;       // 100000
    const int E = in_sizes[1] / 2;         // 3200000
    const int* src = ei;
    const int* dst = ei + E;

    const int NBIN = (N + 255) / 256;      // 391

    // ---- workspace layout (16B-aligned blocks); gather tables have extra zero row N ----
    char* p = (char*)d_ws;
    const size_t ROWS = (size_t)(N + 1) * 64 * 2;
    ushort_t* xb  = (ushort_t*)p;  p += ROWS;
    ushort_t* zb  = (ushort_t*)p;  p += ROWS;
    ushort_t* h1b = (ushort_t*)p;  p += ROWS;
    ushort_t* h2b = (ushort_t*)p;  p += ROWS;
    ushort_t* w1f = (ushort_t*)p;  p += 3 * 14 * 512 * 2;
    ushort_t* w2f = (ushort_t*)p;  p += 3 * 16 * 512 * 2;
    ushort_t* linf= (ushort_t*)p;  p += 32 * 512 * 2;
    int* ghist    = (int*)p;       p += 512 * 4;
    int* gcnt     = (int*)p;       p += 512 * 4;     // contiguous with ghist for one memset
    int* binstart = (int*)p;       p += 512 * 4;
    int* nrs      = (int*)p;       p += (size_t)(N + 4) * 4;
    int* ndeg     = (int*)p;       p += (size_t)(N + 4) * 4;
    uint_t* packed = (uint_t*)p;   p += (size_t)E * 4;
    int* srcsorted = (int*)p;      // E + NBIN*4096 + 64 entries (prefetch slack)

    ushort_t* hbs[3] = {xb, h1b, h2b};

    const int BLK = 256;
    const int NP1 = (E + P1_CHUNK - 1) / P1_CHUNK;   // 782
    const int NXBLK = (N * 16 + BLK - 1) / BLK;      // 6250
    const int NBUCK = (N + 63) / 64;                 // 1563
    const int NPAIR = (N + 1) / 2;                   // nodes per wave = 2
    dim3 blk(BLK);
    dim3 grid_agg(((size_t)NPAIR * 64 + BLK - 1) / BLK);

    // ---- setup (conv + bhist fused) then scan + 2-pass radix CSR build ----
    hipMemsetAsync(ghist, 0, 1024 * sizeof(int), stream);   // ghist + gcnt
    setup_kernel<<<NXBLK + 32 + NP1, blk, 0, stream>>>(x, w1, w2, lin_w, dst,
                                                       xb, h1b, h2b,
                                                       w1f, w2f, linf, ghist, N, E, NXBLK);
    binscan_kernel<<<1, blk, 0, stream>>>(ghist, binstart);
    pass1_kernel<<<NP1, blk, 0, stream>>>(src, dst, binstart, gcnt, packed, E);
    pass2_kernel<<<NBIN, blk, 0, stream>>>(packed, ghist, binstart, srcsorted, nrs, ndeg, N);

    // ---- layers 1,2 ----
    for (int l = 0; l < 2; l++) {
        agg_kernel<<<grid_agg, blk, 0, stream>>>(hbs[l], nrs, ndeg, srcsorted, eps + l, zb, N);
        mlp_kernel<0><<<NBUCK, blk, 0, stream>>>(zb,
                                                 w1f + (size_t)l * 14 * 512,
                                                 b1 + (size_t)l * HID2,
                                                 w2f + (size_t)l * 16 * 512,
                                                 b2 + (size_t)l * HID,
                                                 hbs[l + 1],
                                                 nullptr, nullptr, nullptr,
                                                 nullptr, nullptr, nullptr, N);
    }
    // ---- layer 3 + fused final ----
    agg_kernel<<<grid_agg, blk, 0, stream>>>(h2b, nrs, ndeg, srcsorted, eps + 2, zb, N);
    mlp_kernel<1><<<NBUCK, blk, 0, stream>>>(zb,
                                             w1f + 2 * 14 * 512,
                                             b1 + 2 * HID2,
                                             w2f + 2 * 16 * 512,
                                             b2 + 2 * HID,
                                             nullptr,
                                             xb, h1b, h2b,
                                             linf, lin_b, out, N);
}

// Round 5
// 390.827 us; speedup vs baseline: 1.0736x; 1.0736x over previous
//
#include <hip/hip_runtime.h>

#define HID 52
#define HID2 104
#define P1_CHUNK 8192
#define NBIN_MAX 512      // bins of 256 nodes; N <= 131072
#define HSTRIDE 136

typedef unsigned short ushort_t;
typedef unsigned int uint_t;
typedef short bf16x8 __attribute__((ext_vector_type(8)));
typedef float f32x4 __attribute__((ext_vector_type(4)));
typedef float f32x2 __attribute__((ext_vector_type(2)));

__device__ __forceinline__ ushort_t f2bf(float f) {
    union { float f; uint_t u; } c; c.f = f;
    uint_t u = c.u + 0x7FFFu + ((c.u >> 16) & 1u);   // RNE
    return (ushort_t)(u >> 16);
}
__device__ __forceinline__ float bflo(uint_t u) {
    union { uint_t u; float f; } c; c.u = u << 16; return c.f;
}
__device__ __forceinline__ float bfhi(uint_t u) {
    union { uint_t u; float f; } c; c.u = u & 0xFFFF0000u; return c.f;
}
// raw pair: (a,b) reinterpreted as two f32 -> the two ODD (hi) channels, noisy-mantissa
__device__ __forceinline__ f32x2 rawpair(uint_t a, uint_t b) {
    union { uint_t u; float f; } ca, cb; ca.u = a; cb.u = b;
    return (f32x2){ca.f, cb.f};
}
// shifted pair: (a<<16, b<<16) -> the two EVEN (lo) channels, exact
__device__ __forceinline__ f32x2 shlpair(uint_t a, uint_t b) {
    union { uint_t u; float f; } ca, cb; ca.u = a << 16; cb.u = b << 16;
    return (f32x2){ca.f, cb.f};
}
// in-place packed add: a += b in ONE VOP3P instr ("+v" ties dst=src0)
__device__ __forceinline__ void pkacc(f32x2& a, f32x2 b) {
    asm("v_pk_add_f32 %0, %0, %1" : "+v"(a) : "v"(b));
}
// cross-lane xor within 32-lane halves via ds_swizzle BitMode (imm = (xor<<10)|0x1F)
template<int IMM>
__device__ __forceinline__ f32x2 swz2(f32x2 v) {
    union { float f; int i; } a, b; a.f = v.x; b.f = v.y;
    int ra = __builtin_amdgcn_ds_swizzle(a.i, IMM);
    int rb = __builtin_amdgcn_ds_swizzle(b.i, IMM);
    union { int i; float f; } c, d; c.i = ra; d.i = rb;
    return (f32x2){c.f, d.f};
}

// ---------- fused setup: conv_x + zero pad rows + conv_w + bhist ----------
// ghist/gcnt are pre-zeroed by a hipMemsetAsync before this kernel.
__global__ __launch_bounds__(256) void setup_kernel(const float* __restrict__ x,
                                                    const float* __restrict__ w1,
                                                    const float* __restrict__ w2,
                                                    const float* __restrict__ lin_w,
                                                    const int* __restrict__ dst,
                                                    ushort_t* __restrict__ xb,
                                                    ushort_t* __restrict__ h1b,
                                                    ushort_t* __restrict__ h2b,
                                                    ushort_t* __restrict__ w1f,
                                                    ushort_t* __restrict__ w2f,
                                                    ushort_t* __restrict__ linf,
                                                    int* __restrict__ ghist,
                                                    int n, int E, int nxblk) {
    __shared__ int lh[NBIN_MAX];
    int blk = blockIdx.x;
    int tid = threadIdx.x;
    if (blk < nxblk) {
        int t = blk * 256 + tid;
        if (t >= n * 16) return;
        int node = t >> 4, pp = t & 15;
        int c0 = pp * 4;
        ushort_t o[4];
#pragma unroll
        for (int j = 0; j < 4; j++) {
            int c = c0 + j;
            o[j] = (c < HID) ? f2bf(x[(size_t)node * HID + c]) : 0;
        }
        uint_t u0 = (uint_t)o[0] | ((uint_t)o[1] << 16);
        uint_t u1 = (uint_t)o[2] | ((uint_t)o[3] << 16);
        *(uint2*)(xb + (size_t)node * 64 + c0) = make_uint2(u0, u1);
        return;
    }
    if (blk == nxblk) {
        ushort_t* arr = (tid < 64) ? xb : (tid < 128) ? h1b : h2b;  // 192-255 dup h2b: benign
        arr[(size_t)n * 64 + (tid & 63)] = 0;
        return;
    }
    if (blk < nxblk + 32) {
        int gid = (blk - nxblk - 1) * 4 + (tid >> 6);
        int lane = tid & 63;
        if (gid >= 122) return;
        int m = lane & 15, q = lane >> 4;
        ushort_t o[8];
        ushort_t* dstp;
        if (gid < 42) {
            int l = gid / 14, r = gid % 14, ct = r >> 1, ks = r & 1;
            int nn = ct * 16 + m;
#pragma unroll
            for (int j = 0; j < 8; j++) {
                int k = ks * 32 + q * 8 + j;
                o[j] = (k < HID && nn < HID2) ? f2bf(w1[((size_t)l * HID + k) * HID2 + nn]) : 0;
            }
            dstp = w1f + ((size_t)(l * 14 + ct * 2 + ks) * 64 + lane) * 8;
        } else if (gid < 90) {
            int g2 = gid - 42, l = g2 / 16, r = g2 % 16, ct = r >> 2, ks = r & 3;
            int nn = ct * 16 + m;
#pragma unroll
            for (int j = 0; j < 8; j++) {
                int k = ks * 32 + q * 8 + j;
                o[j] = (k < HID2 && nn < HID) ? f2bf(w2[((size_t)l * HID2 + k) * HID + nn]) : 0;
            }
            dstp = w2f + ((size_t)(l * 16 + ct * 4 + ks) * 64 + lane) * 8;
        } else {
            int g2 = gid - 90, ct = g2 >> 3, ks = g2 & 7;
            int nn = ct * 16 + m;
#pragma unroll
            for (int j = 0; j < 8; j++) {
                int kg = ks * 32 + q * 8 + j;
                int seg = kg >> 6, kk = kg & 63;
                o[j] = (kk < HID && nn < HID) ? f2bf(lin_w[((size_t)seg * HID + kk) * HID + nn]) : 0;
            }
            dstp = linf + ((size_t)(ct * 8 + ks) * 64 + lane) * 8;
        }
        uint4 u;
        u.x = (uint_t)o[0] | ((uint_t)o[1] << 16);
        u.y = (uint_t)o[2] | ((uint_t)o[3] << 16);
        u.z = (uint_t)o[4] | ((uint_t)o[5] << 16);
        u.w = (uint_t)o[6] | ((uint_t)o[7] << 16);
        *(uint4*)dstp = u;
        return;
    }
    // ---- bhist section ----
    int eblk = blk - nxblk - 32;
    lh[tid] = 0; lh[tid + 256] = 0;
    __syncthreads();
    int base = eblk * P1_CHUNK;
    int cend = min(P1_CHUNK, E - base);
    for (int i = tid; i < cend; i += 256) atomicAdd(&lh[dst[base + i] >> 8], 1);
    __syncthreads();
    int cc = lh[tid];       if (cc) atomicAdd(&ghist[tid], cc);
    cc = lh[tid + 256];     if (cc) atomicAdd(&ghist[tid + 256], cc);
}

// ---------- binstart: one-block exclusive scan over the 512-bin histogram ----------
__global__ __launch_bounds__(256) void binscan_kernel(const int* __restrict__ ghist,
                                                      int* __restrict__ binstart) {
    __shared__ int ps[256];
    int tid = threadIdx.x;
    int g0 = ghist[2 * tid], g1 = ghist[2 * tid + 1];
    int pair = g0 + g1;
    ps[tid] = pair;
    __syncthreads();
    for (int off = 1; off < 256; off <<= 1) {
        int t = (tid >= off) ? ps[tid - off] : 0;
        __syncthreads();
        ps[tid] += t;
        __syncthreads();
    }
    int ex = ps[tid] - pair;
    binstart[2 * tid] = ex;
    binstart[2 * tid + 1] = ex + g0;
}

// ---------- pass 1: bin-partition with LDS staging (write-combining) ----------
// r4 lesson: direct scatter -> 4B global writes -> WRITE_SIZE 23->75MB (HBM write
// amplification across XCDs). Staging is mandatory. r3 lesson: chunk=4096 halves
// bin-run length -> worse packed coalescing. So: chunk=8192 staged (r2's 50.6us
// form) + hoisted binstart scan (one scan instead of two) + fused diff[b] =
// gbase[b]-sst[b] (3 LDS reads/edge in phase 3 instead of 4).
__global__ __launch_bounds__(256) void pass1_kernel(const int* __restrict__ src,
                                                    const int* __restrict__ dst,
                                                    const int* __restrict__ binstart,
                                                    int* __restrict__ gcnt,
                                                    uint_t* __restrict__ packed, int E) {
    __shared__ uint_t stage[P1_CHUNK];
    __shared__ ushort_t sbin[P1_CHUNK];
    __shared__ int cnt[NBIN_MAX];
    __shared__ int sst[NBIN_MAX];
    __shared__ int curs[NBIN_MAX];
    __shared__ int diff[NBIN_MAX];
    __shared__ int ps[256];
    int tid = threadIdx.x;
    int b0 = 2 * tid, b1 = 2 * tid + 1;
    cnt[b0] = 0; cnt[b1] = 0;
    __syncthreads();
    int base = blockIdx.x * P1_CHUNK;
    int cend = min(P1_CHUNK, E - base);
    for (int i = tid; i < cend; i += 256) atomicAdd(&cnt[dst[base + i] >> 8], 1);
    __syncthreads();
    int c0 = cnt[b0], c1 = cnt[b1];
    int pair = c0 + c1;
    ps[tid] = pair;
    __syncthreads();
    for (int off = 1; off < 256; off <<= 1) {
        int t = (tid >= off) ? ps[tid - off] : 0;
        __syncthreads();
        ps[tid] += t;
        __syncthreads();
    }
    int ex = ps[tid] - pair;
    int s0 = ex, s1 = ex + c0;
    sst[b0] = s0;  curs[b0] = s0;
    sst[b1] = s1;  curs[b1] = s1;
    int g0 = c0 ? (binstart[b0] + atomicAdd(&gcnt[b0], c0)) : 0;
    int g1 = c1 ? (binstart[b1] + atomicAdd(&gcnt[b1], c1)) : 0;
    diff[b0] = g0 - s0;
    diff[b1] = g1 - s1;
    __syncthreads();
    for (int i = tid; i < cend; i += 256) {
        int d = dst[base + i];
        int s = src[base + i];
        int b = d >> 8;
        int pos = atomicAdd(&curs[b], 1);
        stage[pos] = ((uint_t)s << 8) | (uint_t)(d & 255);
        sbin[pos] = (ushort_t)b;
    }
    __syncthreads();
    for (int i = tid; i < cend; i += 256) {
        packed[diff[sbin[i]] + i] = stage[i];
    }
}

// ---------- pass 2: per-bin counting sort (plain node key), padded runs ----------
__global__ __launch_bounds__(256) void pass2_kernel(const uint_t* __restrict__ packed,
                                                    const int* __restrict__ ghist,
                                                    const int* __restrict__ binstart,
                                                    int* __restrict__ srcsorted,
                                                    int* __restrict__ nrs,
                                                    int* __restrict__ ndeg, int N) {
    __shared__ int ps[256];
    __shared__ int hist[256];
    __shared__ int curs[256];
    int b = blockIdx.x;
    int tid = threadIdx.x;
    hist[tid] = 0;
    __syncthreads();
    int beg = binstart[b];
    int end = beg + ghist[b];
    int obase = beg + b * 4096;
    for (int i = beg + tid; i < end; i += 256) atomicAdd(&hist[packed[i] & 255u], 1);
    __syncthreads();
    int v = hist[tid];
    int pv = (v + 15) & ~15;
    ps[tid] = pv;
    __syncthreads();
    for (int off = 1; off < 256; off <<= 1) {
        int t = (tid >= off) ? ps[tid - off] : 0;
        __syncthreads();
        ps[tid] += t;
        __syncthreads();
    }
    int start = obase + ps[tid] - pv;
    int node = b * 256 + tid;
    if (node < N) { nrs[node] = start; ndeg[node] = pv; }
    curs[tid] = start;
    __syncthreads();
    for (int i = beg + tid; i < end; i += 256) {
        uint_t p = packed[i];
        int pos = atomicAdd(&curs[p & 255u], 1);
        srcsorted[pos] = (int)(p >> 8);
    }
    __syncthreads();
    for (int i = start + v; i < start + pv; i++) srcsorted[i] = N;   // zero-row pads
}

// ---------- aggregation: 2 nodes/wave (lane halves), 8 row-gathers in flight ----------
// At the ~3.45 TB/s L2-miss wall for this gather pattern (r2 A/B: 2x concurrency -> +5% BW).
__global__ __launch_bounds__(256) void agg_kernel(const ushort_t* __restrict__ hb,
                                                  const int* __restrict__ nrs,
                                                  const int* __restrict__ ndeg,
                                                  const int* __restrict__ srcsorted,
                                                  const float* __restrict__ eps,
                                                  ushort_t* __restrict__ zb, int n) {
    int wpair = (blockIdx.x * blockDim.x + threadIdx.x) >> 6;
    int lane = threadIdx.x & 63;
    int half = lane >> 5;
    int wid = wpair * 2 + half;
    bool valid = (wid < n);
    int node = valid ? wid : (n - 1);
    int hl = lane & 31;
    int g = hl >> 3;                         // 0..3 group within half
    int sub = lane & 7;
    int beg = nrs[node];
    int total = valid ? ndeg[node] : 0;      // multiple of 16
    const char* hc = (const char*)hb;        // uniform base (SGPR)
    const char* sp = (const char*)srcsorted; // uniform base (SGPR)
    unsigned lbB = (unsigned)sub * 16u;      // byte offset of lane's 16B row segment
    unsigned bo = (unsigned)(beg + g) * 4u;  // byte offset of lane's index stream

    // O*=(odd ch, noisy-hi raw) E*=(even ch exact); A: even rows, B: odd rows
    f32x2 AO0 = {0,0}, AO1 = {0,0}, AE0 = {0,0}, AE1 = {0,0};
    f32x2 BO0 = {0,0}, BO1 = {0,0}, BE0 = {0,0}, BE1 = {0,0};
    if (total > 0) {
        int f0 = *(const int*)(sp + bo);
        int f1 = *(const int*)(sp + bo + 16);
        int f2 = *(const int*)(sp + bo + 32);
        int f3 = *(const int*)(sp + bo + 48);
        int f4 = *(const int*)(sp + bo + 64);
        int f5 = *(const int*)(sp + bo + 80);
        int f6 = *(const int*)(sp + bo + 96);
        int f7 = *(const int*)(sp + bo + 112);
        for (int b = 0; b < total; b += 32) {
            bool ok = (b + 16) < total;
            int e0 = f0, e1 = f1, e2 = f2, e3 = f3;
            int e4 = ok ? f4 : n, e5 = ok ? f5 : n;
            int e6 = ok ? f6 : n, e7 = ok ? f7 : n;
            f0 = *(const int*)(sp + bo + 128);
            f1 = *(const int*)(sp + bo + 144);
            f2 = *(const int*)(sp + bo + 160);
            f3 = *(const int*)(sp + bo + 176);
            f4 = *(const int*)(sp + bo + 192);
            f5 = *(const int*)(sp + bo + 208);
            f6 = *(const int*)(sp + bo + 224);
            f7 = *(const int*)(sp + bo + 240);
            bo += 128;
            uint4 v0 = *(const uint4*)(hc + (((unsigned)e0 << 7) + lbB));
            uint4 v1 = *(const uint4*)(hc + (((unsigned)e1 << 7) + lbB));
            uint4 v2 = *(const uint4*)(hc + (((unsigned)e2 << 7) + lbB));
            uint4 v3 = *(const uint4*)(hc + (((unsigned)e3 << 7) + lbB));
            uint4 v4 = *(const uint4*)(hc + (((unsigned)e4 << 7) + lbB));
            uint4 v5 = *(const uint4*)(hc + (((unsigned)e5 << 7) + lbB));
            uint4 v6 = *(const uint4*)(hc + (((unsigned)e6 << 7) + lbB));
            uint4 v7 = *(const uint4*)(hc + (((unsigned)e7 << 7) + lbB));
            pkacc(AO0, rawpair(v0.x, v0.y)); pkacc(AO1, rawpair(v0.z, v0.w));
            pkacc(AE0, shlpair(v0.x, v0.y)); pkacc(AE1, shlpair(v0.z, v0.w));
            pkacc(BO0, rawpair(v1.x, v1.y)); pkacc(BO1, rawpair(v1.z, v1.w));
            pkacc(BE0, shlpair(v1.x, v1.y)); pkacc(BE1, shlpair(v1.z, v1.w));
            pkacc(AO0, rawpair(v2.x, v2.y)); pkacc(AO1, rawpair(v2.z, v2.w));
            pkacc(AE0, shlpair(v2.x, v2.y)); pkacc(AE1, shlpair(v2.z, v2.w));
            pkacc(BO0, rawpair(v3.x, v3.y)); pkacc(BO1, rawpair(v3.z, v3.w));
            pkacc(BE0, shlpair(v3.x, v3.y)); pkacc(BE1, shlpair(v3.z, v3.w));
            pkacc(AO0, rawpair(v4.x, v4.y)); pkacc(AO1, rawpair(v4.z, v4.w));
            pkacc(AE0, shlpair(v4.x, v4.y)); pkacc(AE1, shlpair(v4.z, v4.w));
            pkacc(BO0, rawpair(v5.x, v5.y)); pkacc(BO1, rawpair(v5.z, v5.w));
            pkacc(BE0, shlpair(v5.x, v5.y)); pkacc(BE1, shlpair(v5.z, v5.w));
            pkacc(AO0, rawpair(v6.x, v6.y)); pkacc(AO1, rawpair(v6.z, v6.w));
            pkacc(AE0, shlpair(v6.x, v6.y)); pkacc(AE1, shlpair(v6.z, v6.w));
            pkacc(BO0, rawpair(v7.x, v7.y)); pkacc(BO1, rawpair(v7.z, v7.w));
            pkacc(BE0, shlpair(v7.x, v7.y)); pkacc(BE1, shlpair(v7.z, v7.w));
        }
    }
    pkacc(AO0, BO0); pkacc(AO1, BO1);
    pkacc(AE0, BE0); pkacc(AE1, BE1);
    // stage 1: xor-8 (sum group pairs), stage 2: xor-16 (sum quads) — within halves
    pkacc(AO0, swz2<0x201F>(AO0)); pkacc(AO1, swz2<0x201F>(AO1));
    pkacc(AE0, swz2<0x201F>(AE0)); pkacc(AE1, swz2<0x201F>(AE1));
    pkacc(AO0, swz2<0x401F>(AO0)); pkacc(AO1, swz2<0x401F>(AO1));
    pkacc(AE0, swz2<0x401F>(AE0)); pkacc(AE1, swz2<0x401F>(AE1));
    if (hl < 8 && valid) {
        // channel map in this lane's 8-ch sub-block:
        //   AE0=(c0,c2) AO0=(c1,c3) AE1=(c4,c6) AO1=(c5,c7)
        float sc = 1.0f + eps[0];
        uint4 sv = *(const uint4*)(hb + (size_t)wid * 64 + hl * 8);
        float o0 = fmaf(sc, bflo(sv.x), AE0.x), o1 = fmaf(sc, bfhi(sv.x), AO0.x);
        float o2 = fmaf(sc, bflo(sv.y), AE0.y), o3 = fmaf(sc, bfhi(sv.y), AO0.y);
        float o4 = fmaf(sc, bflo(sv.z), AE1.x), o5 = fmaf(sc, bfhi(sv.z), AO1.x);
        float o6 = fmaf(sc, bflo(sv.w), AE1.y), o7 = fmaf(sc, bfhi(sv.w), AO1.y);
        uint4 u;
        u.x = (uint_t)f2bf(o0) | ((uint_t)f2bf(o1) << 16);
        u.y = (uint_t)f2bf(o2) | ((uint_t)f2bf(o3) << 16);
        u.z = (uint_t)f2bf(o4) | ((uint_t)f2bf(o5) << 16);
        u.w = (uint_t)f2bf(o6) | ((uint_t)f2bf(o7) << 16);
        *(uint4*)(zb + (size_t)wid * 64 + hl * 8) = u;
    }
}

// ---------- MFMA fused 2-layer MLP; LAST=1 also fuses the final concat linear ----------
template<int LAST>
__global__ __launch_bounds__(256) void mlp_kernel(const ushort_t* __restrict__ zb,
                                                  const ushort_t* __restrict__ w1f,
                                                  const float* __restrict__ b1,
                                                  const ushort_t* __restrict__ w2f,
                                                  const float* __restrict__ b2,
                                                  ushort_t* __restrict__ hbout,
                                                  const ushort_t* __restrict__ xb,
                                                  const ushort_t* __restrict__ h1b,
                                                  const ushort_t* __restrict__ h2b,
                                                  const ushort_t* __restrict__ linf,
                                                  const float* __restrict__ lin_b,
                                                  float* __restrict__ out, int n) {
    __shared__ ushort_t hid[64 * HSTRIDE];
    __shared__ ushort_t h3t[LAST ? 64 * 68 : 1];
    int tid = threadIdx.x;
    int w = tid >> 6, lane = tid & 63, m = lane & 15, q = lane >> 4;
    for (int i = tid; i < 64 * 32; i += 256) {
        int r = i >> 5, c = HID2 + (i & 31);
        hid[r * HSTRIDE + c] = 0;
    }
    __syncthreads();

    int nb = blockIdx.x * 64 + w * 16;
    f32x4 acc1[7];
#pragma unroll
    for (int ct = 0; ct < 7; ct++) {
        int col = ct * 16 + m;
        float bv = (col < HID2) ? b1[col] : 0.f;
        acc1[ct] = (f32x4){bv, bv, bv, bv};
    }
    int anode = min(nb + m, n - 1);
#pragma unroll
    for (int ks = 0; ks < 2; ks++) {
        bf16x8 a = *(const bf16x8*)(zb + (size_t)anode * 64 + ks * 32 + q * 8);
#pragma unroll
        for (int ct = 0; ct < 7; ct++) {
            bf16x8 b = *(const bf16x8*)(w1f + ((size_t)(ct * 2 + ks) * 64 + lane) * 8);
            acc1[ct] = __builtin_amdgcn_mfma_f32_16x16x32_bf16(a, b, acc1[ct], 0, 0, 0);
        }
    }
#pragma unroll
    for (int ct = 0; ct < 7; ct++) {
#pragma unroll
        for (int r = 0; r < 4; r++) {
            float v = fmaxf(acc1[ct][r], 0.f);
            int row = w * 16 + q * 4 + r;
            hid[row * HSTRIDE + ct * 16 + m] = f2bf(v);
        }
    }
    f32x4 acc2[4];
#pragma unroll
    for (int ct = 0; ct < 4; ct++) {
        int col = ct * 16 + m;
        float bv = (col < HID) ? b2[col] : 0.f;
        acc2[ct] = (f32x4){bv, bv, bv, bv};
    }
#pragma unroll
    for (int ks = 0; ks < 4; ks++) {
        bf16x8 a = *(const bf16x8*)&hid[(w * 16 + m) * HSTRIDE + ks * 32 + q * 8];
#pragma unroll
        for (int ct = 0; ct < 4; ct++) {
            bf16x8 b = *(const bf16x8*)(w2f + ((size_t)(ct * 4 + ks) * 64 + lane) * 8);
            acc2[ct] = __builtin_amdgcn_mfma_f32_16x16x32_bf16(a, b, acc2[ct], 0, 0, 0);
        }
    }

    if (!LAST) {
#pragma unroll
        for (int ct = 0; ct < 4; ct++) {
#pragma unroll
            for (int r = 0; r < 4; r++) {
                int node = nb + q * 4 + r;
                if (node < n) {
                    float v = fmaxf(acc2[ct][r], 0.f);
                    hbout[(size_t)node * 64 + ct * 16 + m] = f2bf(v);
                }
            }
        }
    } else {
        // h3 (C-layout) -> LDS tile; wave-private rows, no barrier needed
#pragma unroll
        for (int ct = 0; ct < 4; ct++) {
#pragma unroll
            for (int r = 0; r < 4; r++) {
                float v = fmaxf(acc2[ct][r], 0.f);
                h3t[(w * 16 + q * 4 + r) * 68 + ct * 16 + m] = f2bf(v);
            }
        }
        // final: [16 x 256] @ [256 x 64]; segs x,h1,h2 from global, h3 from LDS
        f32x4 accF[4];
#pragma unroll
        for (int ct = 0; ct < 4; ct++) {
            int col = ct * 16 + m;
            float bv = (col < HID) ? lin_b[col] : 0.f;
            accF[ct] = (f32x4){bv, bv, bv, bv};
        }
        const ushort_t* segs[3] = {xb, h1b, h2b};
#pragma unroll
        for (int ks = 0; ks < 8; ks++) {
            bf16x8 a;
            if (ks < 6) {
                const ushort_t* p = segs[ks >> 1];
                a = *(const bf16x8*)(p + (size_t)anode * 64 + (ks & 1) * 32 + q * 8);
            } else {
                a = *(const bf16x8*)&h3t[(w * 16 + m) * 68 + (ks & 1) * 32 + q * 8];
            }
#pragma unroll
            for (int ct = 0; ct < 4; ct++) {
                bf16x8 b = *(const bf16x8*)(linf + ((size_t)(ct * 8 + ks) * 64 + lane) * 8);
                accF[ct] = __builtin_amdgcn_mfma_f32_16x16x32_bf16(a, b, accF[ct], 0, 0, 0);
            }
        }
#pragma unroll
        for (int ct = 0; ct < 4; ct++) {
            int col = ct * 16 + m;
            if (col < HID) {
#pragma unroll
                for (int r = 0; r < 4; r++) {
                    int node = nb + q * 4 + r;
                    if (node < n)
                        out[(size_t)node * HID + col] = accF[ct][r];
                }
            }
        }
    }
}

extern "C" void kernel_launch(void* const* d_in, const int* in_sizes, int n_in,
                              void* d_out, int out_size, void* d_ws, size_t ws_size,
                              hipStream_t stream) {
    const float* x     = (const float*)d_in[0];
    const int*   ei    = (const int*)d_in[1];
    const float* w1    = (const float*)d_in[2];
    const float* b1    = (const float*)d_in[3];
    const float* w2    = (const float*)d_in[4];
    const float* b2    = (const float*)d_in[5];
    const float* eps   = (const float*)d_in[6];
    const float* lin_w = (const float*)d_in[7];
    const float* lin_b = (const float*)d_in[8];
    float* out = (float*)d_out;

    const int N = in_sizes[0] / HID;       // 100000
    const int E = in_sizes[1] / 2;         // 3200000
    const int* src = ei;
    const int* dst = ei + E;

    const int NBIN = (N + 255) / 256;      // 391

    // ---- workspace layout (16B-aligned blocks); gather tables have extra zero row N ----
    char* p = (char*)d_ws;
    const size_t ROWS = (size_t)(N + 1) * 64 * 2;
    ushort_t* xb  = (ushort_t*)p;  p += ROWS;
    ushort_t* zb  = (ushort_t*)p;  p += ROWS;
    ushort_t* h1b = (ushort_t*)p;  p += ROWS;
    ushort_t* h2b = (ushort_t*)p;  p += ROWS;
    ushort_t* w1f = (ushort_t*)p;  p += 3 * 14 * 512 * 2;
    ushort_t* w2f = (ushort_t*)p;  p += 3 * 16 * 512 * 2;
    ushort_t* linf= (ushort_t*)p;  p += 32 * 512 * 2;
    int* ghist    = (int*)p;       p += 512 * 4;
    int* gcnt     = (int*)p;       p += 512 * 4;     // contiguous with ghist for one memset
    int* binstart = (int*)p;       p += 512 * 4;
    int* nrs      = (int*)p;       p += (size_t)(N + 4) * 4;
    int* ndeg     = (int*)p;       p += (size_t)(N + 4) * 4;
    uint_t* packed = (uint_t*)p;   p += (size_t)E * 4;
    int* srcsorted = (int*)p;      // E + NBIN*4096 + 64 entries (prefetch slack)

    ushort_t* hbs[3] = {xb, h1b, h2b};

    const int BLK = 256;
    const int NP1 = (E + P1_CHUNK - 1) / P1_CHUNK;   // 391
    const int NXBLK = (N * 16 + BLK - 1) / BLK;      // 6250
    const int NBUCK = (N + 63) / 64;                 // 1563
    const int NPAIR = (N + 1) / 2;                   // nodes per wave = 2
    dim3 blk(BLK);
    dim3 grid_agg(((size_t)NPAIR * 64 + BLK - 1) / BLK);

    // ---- setup (conv + bhist fused) then scan + 2-pass radix CSR build ----
    hipMemsetAsync(ghist, 0, 1024 * sizeof(int), stream);   // ghist + gcnt
    setup_kernel<<<NXBLK + 32 + NP1, blk, 0, stream>>>(x, w1, w2, lin_w, dst,
                                                       xb, h1b, h2b,
                                                       w1f, w2f, linf, ghist, N, E, NXBLK);
    binscan_kernel<<<1, blk, 0, stream>>>(ghist, binstart);
    pass1_kernel<<<NP1, blk, 0, stream>>>(src, dst, binstart, gcnt, packed, E);
    pass2_kernel<<<NBIN, blk, 0, stream>>>(packed, ghist, binstart, srcsorted, nrs, ndeg, N);

    // ---- layers 1,2 ----
    for (int l = 0; l < 2; l++) {
        agg_kernel<<<grid_agg, blk, 0, stream>>>(hbs[l], nrs, ndeg, srcsorted, eps + l, zb, N);
        mlp_kernel<0><<<NBUCK, blk, 0, stream>>>(zb,
                                                 w1f + (size_t)l * 14 * 512,
                                                 b1 + (size_t)l * HID2,
                                                 w2f + (size_t)l * 16 * 512,
                                                 b2 + (size_t)l * HID,
                                                 hbs[l + 1],
                                                 nullptr, nullptr, nullptr,
                                                 nullptr, nullptr, nullptr, N);
    }
    // ---- layer 3 + fused final ----
    agg_kernel<<<grid_agg, blk, 0, stream>>>(h2b, nrs, ndeg, srcsorted, eps + 2, zb, N);
    mlp_kernel<1><<<NBUCK, blk, 0, stream>>>(zb,
                                             w1f + 2 * 14 * 512,
                                             b1 + 2 * HID2,
                                             w2f + 2 * 16 * 512,
                                             b2 + 2 * HID,
                                             nullptr,
                                             xb, h1b, h2b,
                                             linf, lin_b, out, N);
}

// Round 6
// 389.036 us; speedup vs baseline: 1.0785x; 1.0046x over previous
//
#include <hip/hip_runtime.h>

#define HID 52
#define HID2 104
#define P1_CHUNK 8192
#define NBIN_MAX 512      // bins of 256 nodes; N <= 131072
#define HSTRIDE 136

typedef unsigned short ushort_t;
typedef unsigned int uint_t;
typedef short bf16x8 __attribute__((ext_vector_type(8)));
typedef float f32x4 __attribute__((ext_vector_type(4)));
typedef float f32x2 __attribute__((ext_vector_type(2)));

__device__ __forceinline__ ushort_t f2bf(float f) {
    union { float f; uint_t u; } c; c.f = f;
    uint_t u = c.u + 0x7FFFu + ((c.u >> 16) & 1u);   // RNE
    return (ushort_t)(u >> 16);
}
__device__ __forceinline__ float bflo(uint_t u) {
    union { uint_t u; float f; } c; c.u = u << 16; return c.f;
}
__device__ __forceinline__ float bfhi(uint_t u) {
    union { uint_t u; float f; } c; c.u = u & 0xFFFF0000u; return c.f;
}
// raw pair: (a,b) reinterpreted as two f32 -> the two ODD (hi) channels, noisy-mantissa
__device__ __forceinline__ f32x2 rawpair(uint_t a, uint_t b) {
    union { uint_t u; float f; } ca, cb; ca.u = a; cb.u = b;
    return (f32x2){ca.f, cb.f};
}
// shifted pair: (a<<16, b<<16) -> the two EVEN (lo) channels, exact
__device__ __forceinline__ f32x2 shlpair(uint_t a, uint_t b) {
    union { uint_t u; float f; } ca, cb; ca.u = a << 16; cb.u = b << 16;
    return (f32x2){ca.f, cb.f};
}
// in-place packed add: a += b in ONE VOP3P instr ("+v" ties dst=src0)
__device__ __forceinline__ void pkacc(f32x2& a, f32x2 b) {
    asm("v_pk_add_f32 %0, %0, %1" : "+v"(a) : "v"(b));
}
// cross-lane xor within 32-lane halves via ds_swizzle BitMode (imm = (xor<<10)|0x1F)
template<int IMM>
__device__ __forceinline__ f32x2 swz2(f32x2 v) {
    union { float f; int i; } a, b; a.f = v.x; b.f = v.y;
    int ra = __builtin_amdgcn_ds_swizzle(a.i, IMM);
    int rb = __builtin_amdgcn_ds_swizzle(b.i, IMM);
    union { int i; float f; } c, d; c.i = ra; d.i = rb;
    return (f32x2){c.f, d.f};
}

// ---------- fused setup: conv_x + zero pad rows + conv_w + bhist ----------
// ghist/gcnt are pre-zeroed by a hipMemsetAsync before this kernel.
__global__ __launch_bounds__(256) void setup_kernel(const float* __restrict__ x,
                                                    const float* __restrict__ w1,
                                                    const float* __restrict__ w2,
                                                    const float* __restrict__ lin_w,
                                                    const int* __restrict__ dst,
                                                    ushort_t* __restrict__ xb,
                                                    ushort_t* __restrict__ h1b,
                                                    ushort_t* __restrict__ h2b,
                                                    ushort_t* __restrict__ w1f,
                                                    ushort_t* __restrict__ w2f,
                                                    ushort_t* __restrict__ linf,
                                                    int* __restrict__ ghist,
                                                    int n, int E, int nxblk) {
    __shared__ int lh[NBIN_MAX];
    int blk = blockIdx.x;
    int tid = threadIdx.x;
    if (blk < nxblk) {
        int t = blk * 256 + tid;
        if (t >= n * 16) return;
        int node = t >> 4, pp = t & 15;
        int c0 = pp * 4;
        ushort_t o[4];
#pragma unroll
        for (int j = 0; j < 4; j++) {
            int c = c0 + j;
            o[j] = (c < HID) ? f2bf(x[(size_t)node * HID + c]) : 0;
        }
        uint_t u0 = (uint_t)o[0] | ((uint_t)o[1] << 16);
        uint_t u1 = (uint_t)o[2] | ((uint_t)o[3] << 16);
        *(uint2*)(xb + (size_t)node * 64 + c0) = make_uint2(u0, u1);
        return;
    }
    if (blk == nxblk) {
        ushort_t* arr = (tid < 64) ? xb : (tid < 128) ? h1b : h2b;  // 192-255 dup h2b: benign
        arr[(size_t)n * 64 + (tid & 63)] = 0;
        return;
    }
    if (blk < nxblk + 32) {
        int gid = (blk - nxblk - 1) * 4 + (tid >> 6);
        int lane = tid & 63;
        if (gid >= 122) return;
        int m = lane & 15, q = lane >> 4;
        ushort_t o[8];
        ushort_t* dstp;
        if (gid < 42) {
            int l = gid / 14, r = gid % 14, ct = r >> 1, ks = r & 1;
            int nn = ct * 16 + m;
#pragma unroll
            for (int j = 0; j < 8; j++) {
                int k = ks * 32 + q * 8 + j;
                o[j] = (k < HID && nn < HID2) ? f2bf(w1[((size_t)l * HID + k) * HID2 + nn]) : 0;
            }
            dstp = w1f + ((size_t)(l * 14 + ct * 2 + ks) * 64 + lane) * 8;
        } else if (gid < 90) {
            int g2 = gid - 42, l = g2 / 16, r = g2 % 16, ct = r >> 2, ks = r & 3;
            int nn = ct * 16 + m;
#pragma unroll
            for (int j = 0; j < 8; j++) {
                int k = ks * 32 + q * 8 + j;
                o[j] = (k < HID2 && nn < HID) ? f2bf(w2[((size_t)l * HID2 + k) * HID + nn]) : 0;
            }
            dstp = w2f + ((size_t)(l * 16 + ct * 4 + ks) * 64 + lane) * 8;
        } else {
            int g2 = gid - 90, ct = g2 >> 3, ks = g2 & 7;
            int nn = ct * 16 + m;
#pragma unroll
            for (int j = 0; j < 8; j++) {
                int kg = ks * 32 + q * 8 + j;
                int seg = kg >> 6, kk = kg & 63;
                o[j] = (kk < HID && nn < HID) ? f2bf(lin_w[((size_t)seg * HID + kk) * HID + nn]) : 0;
            }
            dstp = linf + ((size_t)(ct * 8 + ks) * 64 + lane) * 8;
        }
        uint4 u;
        u.x = (uint_t)o[0] | ((uint_t)o[1] << 16);
        u.y = (uint_t)o[2] | ((uint_t)o[3] << 16);
        u.z = (uint_t)o[4] | ((uint_t)o[5] << 16);
        u.w = (uint_t)o[6] | ((uint_t)o[7] << 16);
        *(uint4*)dstp = u;
        return;
    }
    // ---- bhist section ----
    int eblk = blk - nxblk - 32;
    lh[tid] = 0; lh[tid + 256] = 0;
    __syncthreads();
    int base = eblk * P1_CHUNK;
    int cend = min(P1_CHUNK, E - base);
    for (int i = tid; i < cend; i += 256) atomicAdd(&lh[dst[base + i] >> 8], 1);
    __syncthreads();
    int cc = lh[tid];       if (cc) atomicAdd(&ghist[tid], cc);
    cc = lh[tid + 256];     if (cc) atomicAdd(&ghist[tid + 256], cc);
}

// ---------- binstart: one-block exclusive scan over the 512-bin histogram ----------
__global__ __launch_bounds__(256) void binscan_kernel(const int* __restrict__ ghist,
                                                      int* __restrict__ binstart) {
    __shared__ int ps[256];
    int tid = threadIdx.x;
    int g0 = ghist[2 * tid], g1 = ghist[2 * tid + 1];
    int pair = g0 + g1;
    ps[tid] = pair;
    __syncthreads();
    for (int off = 1; off < 256; off <<= 1) {
        int t = (tid >= off) ? ps[tid - off] : 0;
        __syncthreads();
        ps[tid] += t;
        __syncthreads();
    }
    int ex = ps[tid] - pair;
    binstart[2 * tid] = ex;
    binstart[2 * tid + 1] = ex + g0;
}

// ---------- pass 1: bin-partition with LDS staging (write-combining) ----------
// r4 lesson: direct scatter -> WRITE_SIZE 23->75MB (HBM write amplification).
// r3 lesson: chunk=4096 halves bin-run length -> worse coalescing. chunk=8192.
__global__ __launch_bounds__(256) void pass1_kernel(const int* __restrict__ src,
                                                    const int* __restrict__ dst,
                                                    const int* __restrict__ binstart,
                                                    int* __restrict__ gcnt,
                                                    uint_t* __restrict__ packed, int E) {
    __shared__ uint_t stage[P1_CHUNK];
    __shared__ ushort_t sbin[P1_CHUNK];
    __shared__ int cnt[NBIN_MAX];
    __shared__ int sst[NBIN_MAX];
    __shared__ int curs[NBIN_MAX];
    __shared__ int diff[NBIN_MAX];
    __shared__ int ps[256];
    int tid = threadIdx.x;
    int b0 = 2 * tid, b1 = 2 * tid + 1;
    cnt[b0] = 0; cnt[b1] = 0;
    __syncthreads();
    int base = blockIdx.x * P1_CHUNK;
    int cend = min(P1_CHUNK, E - base);
    for (int i = tid; i < cend; i += 256) atomicAdd(&cnt[dst[base + i] >> 8], 1);
    __syncthreads();
    int c0 = cnt[b0], c1 = cnt[b1];
    int pair = c0 + c1;
    ps[tid] = pair;
    __syncthreads();
    for (int off = 1; off < 256; off <<= 1) {
        int t = (tid >= off) ? ps[tid - off] : 0;
        __syncthreads();
        ps[tid] += t;
        __syncthreads();
    }
    int ex = ps[tid] - pair;
    int s0 = ex, s1 = ex + c0;
    sst[b0] = s0;  curs[b0] = s0;
    sst[b1] = s1;  curs[b1] = s1;
    int g0 = c0 ? (binstart[b0] + atomicAdd(&gcnt[b0], c0)) : 0;
    int g1 = c1 ? (binstart[b1] + atomicAdd(&gcnt[b1], c1)) : 0;
    diff[b0] = g0 - s0;
    diff[b1] = g1 - s1;
    __syncthreads();
    for (int i = tid; i < cend; i += 256) {
        int d = dst[base + i];
        int s = src[base + i];
        int b = d >> 8;
        int pos = atomicAdd(&curs[b], 1);
        stage[pos] = ((uint_t)s << 8) | (uint_t)(d & 255);
        sbin[pos] = (ushort_t)b;
    }
    __syncthreads();
    for (int i = tid; i < cend; i += 256) {
        packed[diff[sbin[i]] + i] = stage[i];
    }
}

// ---------- pass 2: per-bin counting sort (plain node key), padded runs ----------
__global__ __launch_bounds__(256) void pass2_kernel(const uint_t* __restrict__ packed,
                                                    const int* __restrict__ ghist,
                                                    const int* __restrict__ binstart,
                                                    int* __restrict__ srcsorted,
                                                    int* __restrict__ nrs,
                                                    int* __restrict__ ndeg, int N) {
    __shared__ int ps[256];
    __shared__ int hist[256];
    __shared__ int curs[256];
    int b = blockIdx.x;
    int tid = threadIdx.x;
    hist[tid] = 0;
    __syncthreads();
    int beg = binstart[b];
    int end = beg + ghist[b];
    int obase = beg + b * 4096;
    for (int i = beg + tid; i < end; i += 256) atomicAdd(&hist[packed[i] & 255u], 1);
    __syncthreads();
    int v = hist[tid];
    int pv = (v + 15) & ~15;
    ps[tid] = pv;
    __syncthreads();
    for (int off = 1; off < 256; off <<= 1) {
        int t = (tid >= off) ? ps[tid - off] : 0;
        __syncthreads();
        ps[tid] += t;
        __syncthreads();
    }
    int start = obase + ps[tid] - pv;
    int node = b * 256 + tid;
    if (node < N) { nrs[node] = start; ndeg[node] = pv; }
    curs[tid] = start;
    __syncthreads();
    for (int i = beg + tid; i < end; i += 256) {
        uint_t p = packed[i];
        int pos = atomicAdd(&curs[p & 255u], 1);
        srcsorted[pos] = (int)(p >> 8);
    }
    __syncthreads();
    for (int i = start + v; i < start + pv; i++) srcsorted[i] = N;   // zero-row pads
}

// ---------- FUSED agg + MLP (+ final concat linear when LAST=1) ----------
// Wave w owns nodes blockIdx*64 + w*16 .. +15 — exactly its MFMA A-rows.
// Phase 1: 8 sequential 2-node pair-tasks (lane halves), identical gather body
//   to the r2 agg kernel; z rows -> wave-private LDS tile zt (stride 68, h3t
//   layout). No barrier between phases (wave-private rows).
// Phase 2: existing MFMA MLP with A-frags read from zt instead of global zb.
// Deletes 3 mlp dispatches + the 75 MB zb round-trip on the walled fetch path.
// Gather concurrency per wave unchanged (8 in flight); fetch wall indifferent
// to per-wave serialization (r1->r2 A/B).
template<int LAST>
__global__ __launch_bounds__(256) void aggmlp_kernel(const ushort_t* __restrict__ hb,
                                                     const int* __restrict__ nrs,
                                                     const int* __restrict__ ndeg,
                                                     const int* __restrict__ srcsorted,
                                                     const float* __restrict__ eps,
                                                     const ushort_t* __restrict__ w1f,
                                                     const float* __restrict__ b1,
                                                     const ushort_t* __restrict__ w2f,
                                                     const float* __restrict__ b2,
                                                     ushort_t* __restrict__ hbout,
                                                     const ushort_t* __restrict__ xb,
                                                     const ushort_t* __restrict__ h1b,
                                                     const ushort_t* __restrict__ h2b,
                                                     const ushort_t* __restrict__ linf,
                                                     const float* __restrict__ lin_b,
                                                     float* __restrict__ out, int n) {
    __shared__ ushort_t zt[64 * 68];
    __shared__ ushort_t hid[64 * HSTRIDE];
    __shared__ ushort_t h3t[LAST ? 64 * 68 : 1];
    int tid = threadIdx.x;
    int w = tid >> 6, lane = tid & 63, m = lane & 15, q = lane >> 4;
    int half = lane >> 5, hl = lane & 31, g = hl >> 3, sub = lane & 7;
    for (int i = tid; i < 64 * 32; i += 256) {
        int r = i >> 5, c = HID2 + (i & 31);
        hid[r * HSTRIDE + c] = 0;
    }
    __syncthreads();

    int nb = blockIdx.x * 64 + w * 16;       // this wave's 16 nodes
    float sc = 1.0f + eps[0];
    const char* hc = (const char*)hb;        // uniform base (SGPR)
    const char* sp = (const char*)srcsorted; // uniform base (SGPR)
    unsigned lbB = (unsigned)sub * 16u;      // lane's 16B row segment

    // ---- phase 1: aggregate 16 nodes = 8 pair-tasks ----
#pragma unroll 1
    for (int pt = 0; pt < 8; pt++) {
        int wid = nb + pt * 2 + half;
        bool valid = (wid < n);
        int node = valid ? wid : (n - 1);
        int beg = nrs[node];
        int total = valid ? ndeg[node] : 0;  // multiple of 16
        unsigned bo = (unsigned)(beg + g) * 4u;

        f32x2 AO0 = {0,0}, AO1 = {0,0}, AE0 = {0,0}, AE1 = {0,0};
        f32x2 BO0 = {0,0}, BO1 = {0,0}, BE0 = {0,0}, BE1 = {0,0};
        if (total > 0) {
            int f0 = *(const int*)(sp + bo);
            int f1 = *(const int*)(sp + bo + 16);
            int f2 = *(const int*)(sp + bo + 32);
            int f3 = *(const int*)(sp + bo + 48);
            int f4 = *(const int*)(sp + bo + 64);
            int f5 = *(const int*)(sp + bo + 80);
            int f6 = *(const int*)(sp + bo + 96);
            int f7 = *(const int*)(sp + bo + 112);
            for (int b = 0; b < total; b += 32) {
                bool ok = (b + 16) < total;
                int e0 = f0, e1 = f1, e2 = f2, e3 = f3;
                int e4 = ok ? f4 : n, e5 = ok ? f5 : n;
                int e6 = ok ? f6 : n, e7 = ok ? f7 : n;
                f0 = *(const int*)(sp + bo + 128);
                f1 = *(const int*)(sp + bo + 144);
                f2 = *(const int*)(sp + bo + 160);
                f3 = *(const int*)(sp + bo + 176);
                f4 = *(const int*)(sp + bo + 192);
                f5 = *(const int*)(sp + bo + 208);
                f6 = *(const int*)(sp + bo + 224);
                f7 = *(const int*)(sp + bo + 240);
                bo += 128;
                uint4 v0 = *(const uint4*)(hc + (((unsigned)e0 << 7) + lbB));
                uint4 v1 = *(const uint4*)(hc + (((unsigned)e1 << 7) + lbB));
                uint4 v2 = *(const uint4*)(hc + (((unsigned)e2 << 7) + lbB));
                uint4 v3 = *(const uint4*)(hc + (((unsigned)e3 << 7) + lbB));
                uint4 v4 = *(const uint4*)(hc + (((unsigned)e4 << 7) + lbB));
                uint4 v5 = *(const uint4*)(hc + (((unsigned)e5 << 7) + lbB));
                uint4 v6 = *(const uint4*)(hc + (((unsigned)e6 << 7) + lbB));
                uint4 v7 = *(const uint4*)(hc + (((unsigned)e7 << 7) + lbB));
                pkacc(AO0, rawpair(v0.x, v0.y)); pkacc(AO1, rawpair(v0.z, v0.w));
                pkacc(AE0, shlpair(v0.x, v0.y)); pkacc(AE1, shlpair(v0.z, v0.w));
                pkacc(BO0, rawpair(v1.x, v1.y)); pkacc(BO1, rawpair(v1.z, v1.w));
                pkacc(BE0, shlpair(v1.x, v1.y)); pkacc(BE1, shlpair(v1.z, v1.w));
                pkacc(AO0, rawpair(v2.x, v2.y)); pkacc(AO1, rawpair(v2.z, v2.w));
                pkacc(AE0, shlpair(v2.x, v2.y)); pkacc(AE1, shlpair(v2.z, v2.w));
                pkacc(BO0, rawpair(v3.x, v3.y)); pkacc(BO1, rawpair(v3.z, v3.w));
                pkacc(BE0, shlpair(v3.x, v3.y)); pkacc(BE1, shlpair(v3.z, v3.w));
                pkacc(AO0, rawpair(v4.x, v4.y)); pkacc(AO1, rawpair(v4.z, v4.w));
                pkacc(AE0, shlpair(v4.x, v4.y)); pkacc(AE1, shlpair(v4.z, v4.w));
                pkacc(BO0, rawpair(v5.x, v5.y)); pkacc(BO1, rawpair(v5.z, v5.w));
                pkacc(BE0, shlpair(v5.x, v5.y)); pkacc(BE1, shlpair(v5.z, v5.w));
                pkacc(AO0, rawpair(v6.x, v6.y)); pkacc(AO1, rawpair(v6.z, v6.w));
                pkacc(AE0, shlpair(v6.x, v6.y)); pkacc(AE1, shlpair(v6.z, v6.w));
                pkacc(BO0, rawpair(v7.x, v7.y)); pkacc(BO1, rawpair(v7.z, v7.w));
                pkacc(BE0, shlpair(v7.x, v7.y)); pkacc(BE1, shlpair(v7.z, v7.w));
            }
        }
        pkacc(AO0, BO0); pkacc(AO1, BO1);
        pkacc(AE0, BE0); pkacc(AE1, BE1);
        pkacc(AO0, swz2<0x201F>(AO0)); pkacc(AO1, swz2<0x201F>(AO1));
        pkacc(AE0, swz2<0x201F>(AE0)); pkacc(AE1, swz2<0x201F>(AE1));
        pkacc(AO0, swz2<0x401F>(AO0)); pkacc(AO1, swz2<0x401F>(AO1));
        pkacc(AE0, swz2<0x401F>(AE0)); pkacc(AE1, swz2<0x401F>(AE1));
        if (hl < 8) {
            // AE0=(c0,c2) AO0=(c1,c3) AE1=(c4,c6) AO1=(c5,c7); OOB rows hold
            // clamped-node data -> finite garbage, outputs masked at C-write.
            uint4 sv = *(const uint4*)(hb + (size_t)node * 64 + hl * 8);
            float o0 = fmaf(sc, bflo(sv.x), AE0.x), o1 = fmaf(sc, bfhi(sv.x), AO0.x);
            float o2 = fmaf(sc, bflo(sv.y), AE0.y), o3 = fmaf(sc, bfhi(sv.y), AO0.y);
            float o4 = fmaf(sc, bflo(sv.z), AE1.x), o5 = fmaf(sc, bfhi(sv.z), AO1.x);
            float o6 = fmaf(sc, bflo(sv.w), AE1.y), o7 = fmaf(sc, bfhi(sv.w), AO1.y);
            uint4 u;
            u.x = (uint_t)f2bf(o0) | ((uint_t)f2bf(o1) << 16);
            u.y = (uint_t)f2bf(o2) | ((uint_t)f2bf(o3) << 16);
            u.z = (uint_t)f2bf(o4) | ((uint_t)f2bf(o5) << 16);
            u.w = (uint_t)f2bf(o6) | ((uint_t)f2bf(o7) << 16);
            *(uint4*)(zt + (size_t)(w * 16 + pt * 2 + half) * 68 + hl * 8) = u;
        }
    }
    // no barrier: zt rows are wave-private (written and read by wave w only)

    // ---- phase 2: 2-layer MLP (A from zt) ----
    f32x4 acc1[7];
#pragma unroll
    for (int ct = 0; ct < 7; ct++) {
        int col = ct * 16 + m;
        float bv = (col < HID2) ? b1[col] : 0.f;
        acc1[ct] = (f32x4){bv, bv, bv, bv};
    }
    int anode = min(nb + m, n - 1);
#pragma unroll
    for (int ks = 0; ks < 2; ks++) {
        bf16x8 a = *(const bf16x8*)&zt[(size_t)(w * 16 + m) * 68 + ks * 32 + q * 8];
#pragma unroll
        for (int ct = 0; ct < 7; ct++) {
            bf16x8 b = *(const bf16x8*)(w1f + ((size_t)(ct * 2 + ks) * 64 + lane) * 8);
            acc1[ct] = __builtin_amdgcn_mfma_f32_16x16x32_bf16(a, b, acc1[ct], 0, 0, 0);
        }
    }
#pragma unroll
    for (int ct = 0; ct < 7; ct++) {
#pragma unroll
        for (int r = 0; r < 4; r++) {
            float v = fmaxf(acc1[ct][r], 0.f);
            int row = w * 16 + q * 4 + r;
            hid[row * HSTRIDE + ct * 16 + m] = f2bf(v);
        }
    }
    f32x4 acc2[4];
#pragma unroll
    for (int ct = 0; ct < 4; ct++) {
        int col = ct * 16 + m;
        float bv = (col < HID) ? b2[col] : 0.f;
        acc2[ct] = (f32x4){bv, bv, bv, bv};
    }
#pragma unroll
    for (int ks = 0; ks < 4; ks++) {
        bf16x8 a = *(const bf16x8*)&hid[(w * 16 + m) * HSTRIDE + ks * 32 + q * 8];
#pragma unroll
        for (int ct = 0; ct < 4; ct++) {
            bf16x8 b = *(const bf16x8*)(w2f + ((size_t)(ct * 4 + ks) * 64 + lane) * 8);
            acc2[ct] = __builtin_amdgcn_mfma_f32_16x16x32_bf16(a, b, acc2[ct], 0, 0, 0);
        }
    }

    if (!LAST) {
#pragma unroll
        for (int ct = 0; ct < 4; ct++) {
#pragma unroll
            for (int r = 0; r < 4; r++) {
                int node = nb + q * 4 + r;
                if (node < n) {
                    float v = fmaxf(acc2[ct][r], 0.f);
                    hbout[(size_t)node * 64 + ct * 16 + m] = f2bf(v);
                }
            }
        }
    } else {
        // h3 (C-layout) -> LDS tile; wave-private rows, no barrier needed
#pragma unroll
        for (int ct = 0; ct < 4; ct++) {
#pragma unroll
            for (int r = 0; r < 4; r++) {
                float v = fmaxf(acc2[ct][r], 0.f);
                h3t[(w * 16 + q * 4 + r) * 68 + ct * 16 + m] = f2bf(v);
            }
        }
        // final: [16 x 256] @ [256 x 64]; segs x,h1,h2 from global, h3 from LDS
        f32x4 accF[4];
#pragma unroll
        for (int ct = 0; ct < 4; ct++) {
            int col = ct * 16 + m;
            float bv = (col < HID) ? lin_b[col] : 0.f;
            accF[ct] = (f32x4){bv, bv, bv, bv};
        }
        const ushort_t* segs[3] = {xb, h1b, h2b};
#pragma unroll
        for (int ks = 0; ks < 8; ks++) {
            bf16x8 a;
            if (ks < 6) {
                const ushort_t* p = segs[ks >> 1];
                a = *(const bf16x8*)(p + (size_t)anode * 64 + (ks & 1) * 32 + q * 8);
            } else {
                a = *(const bf16x8*)&h3t[(w * 16 + m) * 68 + (ks & 1) * 32 + q * 8];
            }
#pragma unroll
            for (int ct = 0; ct < 4; ct++) {
                bf16x8 b = *(const bf16x8*)(linf + ((size_t)(ct * 8 + ks) * 64 + lane) * 8);
                accF[ct] = __builtin_amdgcn_mfma_f32_16x16x32_bf16(a, b, accF[ct], 0, 0, 0);
            }
        }
#pragma unroll
        for (int ct = 0; ct < 4; ct++) {
            int col = ct * 16 + m;
            if (col < HID) {
#pragma unroll
                for (int r = 0; r < 4; r++) {
                    int node = nb + q * 4 + r;
                    if (node < n)
                        out[(size_t)node * HID + col] = accF[ct][r];
                }
            }
        }
    }
}

extern "C" void kernel_launch(void* const* d_in, const int* in_sizes, int n_in,
                              void* d_out, int out_size, void* d_ws, size_t ws_size,
                              hipStream_t stream) {
    const float* x     = (const float*)d_in[0];
    const int*   ei    = (const int*)d_in[1];
    const float* w1    = (const float*)d_in[2];
    const float* b1    = (const float*)d_in[3];
    const float* w2    = (const float*)d_in[4];
    const float* b2    = (const float*)d_in[5];
    const float* eps   = (const float*)d_in[6];
    const float* lin_w = (const float*)d_in[7];
    const float* lin_b = (const float*)d_in[8];
    float* out = (float*)d_out;

    const int N = in_sizes[0] / HID;       // 100000
    const int E = in_sizes[1] / 2;         // 3200000
    const int* src = ei;
    const int* dst = ei + E;

    const int NBIN = (N + 255) / 256;      // 391

    // ---- workspace layout (16B-aligned blocks); gather tables have extra zero row N ----
    char* p = (char*)d_ws;
    const size_t ROWS = (size_t)(N + 1) * 64 * 2;
    ushort_t* xb  = (ushort_t*)p;  p += ROWS;
    ushort_t* h1b = (ushort_t*)p;  p += ROWS;
    ushort_t* h2b = (ushort_t*)p;  p += ROWS;
    ushort_t* w1f = (ushort_t*)p;  p += 3 * 14 * 512 * 2;
    ushort_t* w2f = (ushort_t*)p;  p += 3 * 16 * 512 * 2;
    ushort_t* linf= (ushort_t*)p;  p += 32 * 512 * 2;
    int* ghist    = (int*)p;       p += 512 * 4;
    int* gcnt     = (int*)p;       p += 512 * 4;     // contiguous with ghist for one memset
    int* binstart = (int*)p;       p += 512 * 4;
    int* nrs      = (int*)p;       p += (size_t)(N + 4) * 4;
    int* ndeg     = (int*)p;       p += (size_t)(N + 4) * 4;
    uint_t* packed = (uint_t*)p;   p += (size_t)E * 4;
    int* srcsorted = (int*)p;      // E + NBIN*4096 + 64 entries (prefetch slack)

    ushort_t* hbs[3] = {xb, h1b, h2b};

    const int BLK = 256;
    const int NP1 = (E + P1_CHUNK - 1) / P1_CHUNK;   // 391
    const int NXBLK = (N * 16 + BLK - 1) / BLK;      // 6250
    const int NBUCK = (N + 63) / 64;                 // 1563
    dim3 blk(BLK);

    // ---- setup (conv + bhist fused) then scan + 2-pass radix CSR build ----
    hipMemsetAsync(ghist, 0, 1024 * sizeof(int), stream);   // ghist + gcnt
    setup_kernel<<<NXBLK + 32 + NP1, blk, 0, stream>>>(x, w1, w2, lin_w, dst,
                                                       xb, h1b, h2b,
                                                       w1f, w2f, linf, ghist, N, E, NXBLK);
    binscan_kernel<<<1, blk, 0, stream>>>(ghist, binstart);
    pass1_kernel<<<NP1, blk, 0, stream>>>(src, dst, binstart, gcnt, packed, E);
    pass2_kernel<<<NBIN, blk, 0, stream>>>(packed, ghist, binstart, srcsorted, nrs, ndeg, N);

    // ---- layers 1,2 (fused agg+mlp) ----
    for (int l = 0; l < 2; l++) {
        aggmlp_kernel<0><<<NBUCK, blk, 0, stream>>>(hbs[l], nrs, ndeg, srcsorted, eps + l,
                                                    w1f + (size_t)l * 14 * 512,
                                                    b1 + (size_t)l * HID2,
                                                    w2f + (size_t)l * 16 * 512,
                                                    b2 + (size_t)l * HID,
                                                    hbs[l + 1],
                                                    nullptr, nullptr, nullptr,
                                                    nullptr, nullptr, nullptr, N);
    }
    // ---- layer 3 + fused final ----
    aggmlp_kernel<1><<<NBUCK, blk, 0, stream>>>(h2b, nrs, ndeg, srcsorted, eps + 2,
                                                w1f + 2 * 14 * 512,
                                                b1 + 2 * HID2,
                                                w2f + 2 * 16 * 512,
                                                b2 + 2 * HID,
                                                nullptr,
                                                xb, h1b, h2b,
                                                linf, lin_b, out, N);
}

// Round 7
// 387.993 us; speedup vs baseline: 1.0814x; 1.0027x over previous
//
#include <hip/hip_runtime.h>

#define HID 52
#define HID2 104
#define P1_CHUNK 8192
#define NBIN_MAX 512      // bins of 256 nodes; N <= 131072
#define HSTRIDE 136

typedef unsigned short ushort_t;
typedef unsigned int uint_t;
typedef short bf16x8 __attribute__((ext_vector_type(8)));
typedef float f32x4 __attribute__((ext_vector_type(4)));
typedef float f32x2 __attribute__((ext_vector_type(2)));

__device__ __forceinline__ ushort_t f2bf(float f) {
    union { float f; uint_t u; } c; c.f = f;
    uint_t u = c.u + 0x7FFFu + ((c.u >> 16) & 1u);   // RNE
    return (ushort_t)(u >> 16);
}
__device__ __forceinline__ float bflo(uint_t u) {
    union { uint_t u; float f; } c; c.u = u << 16; return c.f;
}
__device__ __forceinline__ float bfhi(uint_t u) {
    union { uint_t u; float f; } c; c.u = u & 0xFFFF0000u; return c.f;
}
// raw pair: (a,b) reinterpreted as two f32 -> the two ODD (hi) channels, noisy-mantissa
__device__ __forceinline__ f32x2 rawpair(uint_t a, uint_t b) {
    union { uint_t u; float f; } ca, cb; ca.u = a; cb.u = b;
    return (f32x2){ca.f, cb.f};
}
// shifted pair: (a<<16, b<<16) -> the two EVEN (lo) channels, exact
__device__ __forceinline__ f32x2 shlpair(uint_t a, uint_t b) {
    union { uint_t u; float f; } ca, cb; ca.u = a << 16; cb.u = b << 16;
    return (f32x2){ca.f, cb.f};
}
// in-place packed add: a += b in ONE VOP3P instr ("+v" ties dst=src0)
__device__ __forceinline__ void pkacc(f32x2& a, f32x2 b) {
    asm("v_pk_add_f32 %0, %0, %1" : "+v"(a) : "v"(b));
}
// cross-lane xor within 32-lane halves via ds_swizzle BitMode (imm = (xor<<10)|0x1F)
template<int IMM>
__device__ __forceinline__ f32x2 swz2(f32x2 v) {
    union { float f; int i; } a, b; a.f = v.x; b.f = v.y;
    int ra = __builtin_amdgcn_ds_swizzle(a.i, IMM);
    int rb = __builtin_amdgcn_ds_swizzle(b.i, IMM);
    union { int i; float f; } c, d; c.i = ra; d.i = rb;
    return (f32x2){c.f, d.f};
}

// ---------- fused setup: conv_x + zero pad rows + conv_w + bhist ----------
// ghist/gcnt are pre-zeroed by a hipMemsetAsync before this kernel.
__global__ __launch_bounds__(256) void setup_kernel(const float* __restrict__ x,
                                                    const float* __restrict__ w1,
                                                    const float* __restrict__ w2,
                                                    const float* __restrict__ lin_w,
                                                    const int* __restrict__ dst,
                                                    ushort_t* __restrict__ xb,
                                                    ushort_t* __restrict__ h1b,
                                                    ushort_t* __restrict__ h2b,
                                                    ushort_t* __restrict__ w1f,
                                                    ushort_t* __restrict__ w2f,
                                                    ushort_t* __restrict__ linf,
                                                    int* __restrict__ ghist,
                                                    int n, int E, int nxblk) {
    __shared__ int lh[NBIN_MAX];
    int blk = blockIdx.x;
    int tid = threadIdx.x;
    if (blk < nxblk) {
        int t = blk * 256 + tid;
        if (t >= n * 16) return;
        int node = t >> 4, pp = t & 15;
        int c0 = pp * 4;
        ushort_t o[4];
#pragma unroll
        for (int j = 0; j < 4; j++) {
            int c = c0 + j;
            o[j] = (c < HID) ? f2bf(x[(size_t)node * HID + c]) : 0;
        }
        uint_t u0 = (uint_t)o[0] | ((uint_t)o[1] << 16);
        uint_t u1 = (uint_t)o[2] | ((uint_t)o[3] << 16);
        *(uint2*)(xb + (size_t)node * 64 + c0) = make_uint2(u0, u1);
        return;
    }
    if (blk == nxblk) {
        ushort_t* arr = (tid < 64) ? xb : (tid < 128) ? h1b : h2b;  // 192-255 dup h2b: benign
        arr[(size_t)n * 64 + (tid & 63)] = 0;
        return;
    }
    if (blk < nxblk + 32) {
        int gid = (blk - nxblk - 1) * 4 + (tid >> 6);
        int lane = tid & 63;
        if (gid >= 122) return;
        int m = lane & 15, q = lane >> 4;
        ushort_t o[8];
        ushort_t* dstp;
        if (gid < 42) {
            int l = gid / 14, r = gid % 14, ct = r >> 1, ks = r & 1;
            int nn = ct * 16 + m;
#pragma unroll
            for (int j = 0; j < 8; j++) {
                int k = ks * 32 + q * 8 + j;
                o[j] = (k < HID && nn < HID2) ? f2bf(w1[((size_t)l * HID + k) * HID2 + nn]) : 0;
            }
            dstp = w1f + ((size_t)(l * 14 + ct * 2 + ks) * 64 + lane) * 8;
        } else if (gid < 90) {
            int g2 = gid - 42, l = g2 / 16, r = g2 % 16, ct = r >> 2, ks = r & 3;
            int nn = ct * 16 + m;
#pragma unroll
            for (int j = 0; j < 8; j++) {
                int k = ks * 32 + q * 8 + j;
                o[j] = (k < HID2 && nn < HID) ? f2bf(w2[((size_t)l * HID2 + k) * HID + nn]) : 0;
            }
            dstp = w2f + ((size_t)(l * 16 + ct * 4 + ks) * 64 + lane) * 8;
        } else {
            int g2 = gid - 90, ct = g2 >> 3, ks = g2 & 7;
            int nn = ct * 16 + m;
#pragma unroll
            for (int j = 0; j < 8; j++) {
                int kg = ks * 32 + q * 8 + j;
                int seg = kg >> 6, kk = kg & 63;
                o[j] = (kk < HID && nn < HID) ? f2bf(lin_w[((size_t)seg * HID + kk) * HID + nn]) : 0;
            }
            dstp = linf + ((size_t)(ct * 8 + ks) * 64 + lane) * 8;
        }
        uint4 u;
        u.x = (uint_t)o[0] | ((uint_t)o[1] << 16);
        u.y = (uint_t)o[2] | ((uint_t)o[3] << 16);
        u.z = (uint_t)o[4] | ((uint_t)o[5] << 16);
        u.w = (uint_t)o[6] | ((uint_t)o[7] << 16);
        *(uint4*)dstp = u;
        return;
    }
    // ---- bhist section ----
    int eblk = blk - nxblk - 32;
    lh[tid] = 0; lh[tid + 256] = 0;
    __syncthreads();
    int base = eblk * P1_CHUNK;
    int cend = min(P1_CHUNK, E - base);
    for (int i = tid; i < cend; i += 256) atomicAdd(&lh[dst[base + i] >> 8], 1);
    __syncthreads();
    int cc = lh[tid];       if (cc) atomicAdd(&ghist[tid], cc);
    cc = lh[tid + 256];     if (cc) atomicAdd(&ghist[tid + 256], cc);
}

// ---------- binstart: one-block exclusive scan over the 512-bin histogram ----------
__global__ __launch_bounds__(256) void binscan_kernel(const int* __restrict__ ghist,
                                                      int* __restrict__ binstart) {
    __shared__ int ps[256];
    int tid = threadIdx.x;
    int g0 = ghist[2 * tid], g1 = ghist[2 * tid + 1];
    int pair = g0 + g1;
    ps[tid] = pair;
    __syncthreads();
    for (int off = 1; off < 256; off <<= 1) {
        int t = (tid >= off) ? ps[tid - off] : 0;
        __syncthreads();
        ps[tid] += t;
        __syncthreads();
    }
    int ex = ps[tid] - pair;
    binstart[2 * tid] = ex;
    binstart[2 * tid + 1] = ex + g0;
}

// ---------- pass 1: bin-partition with LDS staging (write-combining) ----------
// r4 lesson: direct scatter -> WRITE_SIZE 23->75MB (HBM write amplification).
// r3 lesson: chunk=4096 halves bin-run length -> worse coalescing. chunk=8192.
__global__ __launch_bounds__(256) void pass1_kernel(const int* __restrict__ src,
                                                    const int* __restrict__ dst,
                                                    const int* __restrict__ binstart,
                                                    int* __restrict__ gcnt,
                                                    uint_t* __restrict__ packed, int E) {
    __shared__ uint_t stage[P1_CHUNK];
    __shared__ ushort_t sbin[P1_CHUNK];
    __shared__ int cnt[NBIN_MAX];
    __shared__ int sst[NBIN_MAX];
    __shared__ int curs[NBIN_MAX];
    __shared__ int diff[NBIN_MAX];
    __shared__ int ps[256];
    int tid = threadIdx.x;
    int b0 = 2 * tid, b1 = 2 * tid + 1;
    cnt[b0] = 0; cnt[b1] = 0;
    __syncthreads();
    int base = blockIdx.x * P1_CHUNK;
    int cend = min(P1_CHUNK, E - base);
    for (int i = tid; i < cend; i += 256) atomicAdd(&cnt[dst[base + i] >> 8], 1);
    __syncthreads();
    int c0 = cnt[b0], c1 = cnt[b1];
    int pair = c0 + c1;
    ps[tid] = pair;
    __syncthreads();
    for (int off = 1; off < 256; off <<= 1) {
        int t = (tid >= off) ? ps[tid - off] : 0;
        __syncthreads();
        ps[tid] += t;
        __syncthreads();
    }
    int ex = ps[tid] - pair;
    int s0 = ex, s1 = ex + c0;
    sst[b0] = s0;  curs[b0] = s0;
    sst[b1] = s1;  curs[b1] = s1;
    int g0 = c0 ? (binstart[b0] + atomicAdd(&gcnt[b0], c0)) : 0;
    int g1 = c1 ? (binstart[b1] + atomicAdd(&gcnt[b1], c1)) : 0;
    diff[b0] = g0 - s0;
    diff[b1] = g1 - s1;
    __syncthreads();
    for (int i = tid; i < cend; i += 256) {
        int d = dst[base + i];
        int s = src[base + i];
        int b = d >> 8;
        int pos = atomicAdd(&curs[b], 1);
        stage[pos] = ((uint_t)s << 8) | (uint_t)(d & 255);
        sbin[pos] = (ushort_t)b;
    }
    __syncthreads();
    for (int i = tid; i < cend; i += 256) {
        packed[diff[sbin[i]] + i] = stage[i];
    }
}

// ---------- pass 2: per-bin counting sort (plain node key), padded runs ----------
__global__ __launch_bounds__(256) void pass2_kernel(const uint_t* __restrict__ packed,
                                                    const int* __restrict__ ghist,
                                                    const int* __restrict__ binstart,
                                                    int* __restrict__ srcsorted,
                                                    int* __restrict__ nrs,
                                                    int* __restrict__ ndeg, int N) {
    __shared__ int ps[256];
    __shared__ int hist[256];
    __shared__ int curs[256];
    int b = blockIdx.x;
    int tid = threadIdx.x;
    hist[tid] = 0;
    __syncthreads();
    int beg = binstart[b];
    int end = beg + ghist[b];
    int obase = beg + b * 4096;
    for (int i = beg + tid; i < end; i += 256) atomicAdd(&hist[packed[i] & 255u], 1);
    __syncthreads();
    int v = hist[tid];
    int pv = (v + 15) & ~15;
    ps[tid] = pv;
    __syncthreads();
    for (int off = 1; off < 256; off <<= 1) {
        int t = (tid >= off) ? ps[tid - off] : 0;
        __syncthreads();
        ps[tid] += t;
        __syncthreads();
    }
    int start = obase + ps[tid] - pv;
    int node = b * 256 + tid;
    if (node < N) { nrs[node] = start; ndeg[node] = pv; }
    curs[tid] = start;
    __syncthreads();
    for (int i = beg + tid; i < end; i += 256) {
        uint_t p = packed[i];
        int pos = atomicAdd(&curs[p & 255u], 1);
        srcsorted[pos] = (int)(p >> 8);
    }
    __syncthreads();
    for (int i = start + v; i < start + pv; i++) srcsorted[i] = N;   // zero-row pads
}

// ---------- FUSED agg + MLP, cooperative gather (+ final linear when LAST=1) ----------
// r6 lesson: per-wave sequential 16-node walk dropped gather BW 3.5->2.5 TB/s
// (occupancy 50->31%, FETCH +18MB). Fix: phase 1 is COOPERATIVE — per pass p,
// all 4 waves aggregate the contiguous 8-node group [p*8, p*8+8) (wave w takes
// nodes p*8+w*2+half — exactly the r5 split-agg mapping), z rows -> shared zt.
// One barrier, then per-wave MFMA MLP on its 16 zt rows.
// h3t aliases zt (zt fully consumed by acc1 MFMAs before h3t writes; both
// wave-private row ranges in phase 2) -> LDS 25.6KB -> 6 blocks/CU.
template<int LAST>
__global__ __launch_bounds__(256) void aggmlp_kernel(const ushort_t* __restrict__ hb,
                                                     const int* __restrict__ nrs,
                                                     const int* __restrict__ ndeg,
                                                     const int* __restrict__ srcsorted,
                                                     const float* __restrict__ eps,
                                                     const ushort_t* __restrict__ w1f,
                                                     const float* __restrict__ b1,
                                                     const ushort_t* __restrict__ w2f,
                                                     const float* __restrict__ b2,
                                                     ushort_t* __restrict__ hbout,
                                                     const ushort_t* __restrict__ xb,
                                                     const ushort_t* __restrict__ h1b,
                                                     const ushort_t* __restrict__ h2b,
                                                     const ushort_t* __restrict__ linf,
                                                     const float* __restrict__ lin_b,
                                                     float* __restrict__ out, int n) {
    __shared__ ushort_t zt[64 * 68];
    __shared__ ushort_t hid[64 * HSTRIDE];
    int tid = threadIdx.x;
    int w = tid >> 6, lane = tid & 63, m = lane & 15, q = lane >> 4;
    int half = lane >> 5, hl = lane & 31, g = hl >> 3, sub = lane & 7;
    // hid pad-zeroing (cols 104..135); covered by the post-phase1 barrier
    for (int i = tid; i < 64 * 32; i += 256) {
        int r = i >> 5, c = HID2 + (i & 31);
        hid[r * HSTRIDE + c] = 0;
    }

    int nb64 = blockIdx.x * 64;
    int nb = nb64 + w * 16;                  // this wave's 16 MFMA rows
    float sc = 1.0f + eps[0];
    const char* hc = (const char*)hb;        // uniform base (SGPR)
    const char* sp = (const char*)srcsorted; // uniform base (SGPR)
    unsigned lbB = (unsigned)sub * 16u;      // lane's 16B row segment

    // ---- phase 1: cooperative aggregation, 8 passes x 8 contiguous nodes ----
#pragma unroll 1
    for (int pt = 0; pt < 8; pt++) {
        int lrow = pt * 8 + w * 2 + half;    // 0..63 local z row
        int wid = nb64 + lrow;
        bool valid = (wid < n);
        int node = valid ? wid : (n - 1);
        int beg = nrs[node];
        int total = valid ? ndeg[node] : 0;  // multiple of 16
        unsigned bo = (unsigned)(beg + g) * 4u;

        f32x2 AO0 = {0,0}, AO1 = {0,0}, AE0 = {0,0}, AE1 = {0,0};
        f32x2 BO0 = {0,0}, BO1 = {0,0}, BE0 = {0,0}, BE1 = {0,0};
        if (total > 0) {
            int f0 = *(const int*)(sp + bo);
            int f1 = *(const int*)(sp + bo + 16);
            int f2 = *(const int*)(sp + bo + 32);
            int f3 = *(const int*)(sp + bo + 48);
            int f4 = *(const int*)(sp + bo + 64);
            int f5 = *(const int*)(sp + bo + 80);
            int f6 = *(const int*)(sp + bo + 96);
            int f7 = *(const int*)(sp + bo + 112);
            for (int b = 0; b < total; b += 32) {
                bool ok = (b + 16) < total;
                int e0 = f0, e1 = f1, e2 = f2, e3 = f3;
                int e4 = ok ? f4 : n, e5 = ok ? f5 : n;
                int e6 = ok ? f6 : n, e7 = ok ? f7 : n;
                f0 = *(const int*)(sp + bo + 128);
                f1 = *(const int*)(sp + bo + 144);
                f2 = *(const int*)(sp + bo + 160);
                f3 = *(const int*)(sp + bo + 176);
                f4 = *(const int*)(sp + bo + 192);
                f5 = *(const int*)(sp + bo + 208);
                f6 = *(const int*)(sp + bo + 224);
                f7 = *(const int*)(sp + bo + 240);
                bo += 128;
                uint4 v0 = *(const uint4*)(hc + (((unsigned)e0 << 7) + lbB));
                uint4 v1 = *(const uint4*)(hc + (((unsigned)e1 << 7) + lbB));
                uint4 v2 = *(const uint4*)(hc + (((unsigned)e2 << 7) + lbB));
                uint4 v3 = *(const uint4*)(hc + (((unsigned)e3 << 7) + lbB));
                uint4 v4 = *(const uint4*)(hc + (((unsigned)e4 << 7) + lbB));
                uint4 v5 = *(const uint4*)(hc + (((unsigned)e5 << 7) + lbB));
                uint4 v6 = *(const uint4*)(hc + (((unsigned)e6 << 7) + lbB));
                uint4 v7 = *(const uint4*)(hc + (((unsigned)e7 << 7) + lbB));
                pkacc(AO0, rawpair(v0.x, v0.y)); pkacc(AO1, rawpair(v0.z, v0.w));
                pkacc(AE0, shlpair(v0.x, v0.y)); pkacc(AE1, shlpair(v0.z, v0.w));
                pkacc(BO0, rawpair(v1.x, v1.y)); pkacc(BO1, rawpair(v1.z, v1.w));
                pkacc(BE0, shlpair(v1.x, v1.y)); pkacc(BE1, shlpair(v1.z, v1.w));
                pkacc(AO0, rawpair(v2.x, v2.y)); pkacc(AO1, rawpair(v2.z, v2.w));
                pkacc(AE0, shlpair(v2.x, v2.y)); pkacc(AE1, shlpair(v2.z, v2.w));
                pkacc(BO0, rawpair(v3.x, v3.y)); pkacc(BO1, rawpair(v3.z, v3.w));
                pkacc(BE0, shlpair(v3.x, v3.y)); pkacc(BE1, shlpair(v3.z, v3.w));
                pkacc(AO0, rawpair(v4.x, v4.y)); pkacc(AO1, rawpair(v4.z, v4.w));
                pkacc(AE0, shlpair(v4.x, v4.y)); pkacc(AE1, shlpair(v4.z, v4.w));
                pkacc(BO0, rawpair(v5.x, v5.y)); pkacc(BO1, rawpair(v5.z, v5.w));
                pkacc(BE0, shlpair(v5.x, v5.y)); pkacc(BE1, shlpair(v5.z, v5.w));
                pkacc(AO0, rawpair(v6.x, v6.y)); pkacc(AO1, rawpair(v6.z, v6.w));
                pkacc(AE0, shlpair(v6.x, v6.y)); pkacc(AE1, shlpair(v6.z, v6.w));
                pkacc(BO0, rawpair(v7.x, v7.y)); pkacc(BO1, rawpair(v7.z, v7.w));
                pkacc(BE0, shlpair(v7.x, v7.y)); pkacc(BE1, shlpair(v7.z, v7.w));
            }
        }
        pkacc(AO0, BO0); pkacc(AO1, BO1);
        pkacc(AE0, BE0); pkacc(AE1, BE1);
        pkacc(AO0, swz2<0x201F>(AO0)); pkacc(AO1, swz2<0x201F>(AO1));
        pkacc(AE0, swz2<0x201F>(AE0)); pkacc(AE1, swz2<0x201F>(AE1));
        pkacc(AO0, swz2<0x401F>(AO0)); pkacc(AO1, swz2<0x401F>(AO1));
        pkacc(AE0, swz2<0x401F>(AE0)); pkacc(AE1, swz2<0x401F>(AE1));
        if (hl < 8) {
            // AE0=(c0,c2) AO0=(c1,c3) AE1=(c4,c6) AO1=(c5,c7); OOB rows hold
            // clamped-node data -> finite garbage, outputs masked at C-write.
            uint4 sv = *(const uint4*)(hb + (size_t)node * 64 + hl * 8);
            float o0 = fmaf(sc, bflo(sv.x), AE0.x), o1 = fmaf(sc, bfhi(sv.x), AO0.x);
            float o2 = fmaf(sc, bflo(sv.y), AE0.y), o3 = fmaf(sc, bfhi(sv.y), AO0.y);
            float o4 = fmaf(sc, bflo(sv.z), AE1.x), o5 = fmaf(sc, bfhi(sv.z), AO1.x);
            float o6 = fmaf(sc, bflo(sv.w), AE1.y), o7 = fmaf(sc, bfhi(sv.w), AO1.y);
            uint4 u;
            u.x = (uint_t)f2bf(o0) | ((uint_t)f2bf(o1) << 16);
            u.y = (uint_t)f2bf(o2) | ((uint_t)f2bf(o3) << 16);
            u.z = (uint_t)f2bf(o4) | ((uint_t)f2bf(o5) << 16);
            u.w = (uint_t)f2bf(o6) | ((uint_t)f2bf(o7) << 16);
            *(uint4*)(zt + (size_t)lrow * 68 + hl * 8) = u;
        }
    }
    __syncthreads();   // zt rows written cross-wave; hid pad-zeroing also covered

    // ---- phase 2: 2-layer MLP (A from zt) ----
    f32x4 acc1[7];
#pragma unroll
    for (int ct = 0; ct < 7; ct++) {
        int col = ct * 16 + m;
        float bv = (col < HID2) ? b1[col] : 0.f;
        acc1[ct] = (f32x4){bv, bv, bv, bv};
    }
    int anode = min(nb + m, n - 1);
#pragma unroll
    for (int ks = 0; ks < 2; ks++) {
        bf16x8 a = *(const bf16x8*)&zt[(size_t)(w * 16 + m) * 68 + ks * 32 + q * 8];
#pragma unroll
        for (int ct = 0; ct < 7; ct++) {
            bf16x8 b = *(const bf16x8*)(w1f + ((size_t)(ct * 2 + ks) * 64 + lane) * 8);
            acc1[ct] = __builtin_amdgcn_mfma_f32_16x16x32_bf16(a, b, acc1[ct], 0, 0, 0);
        }
    }
#pragma unroll
    for (int ct = 0; ct < 7; ct++) {
#pragma unroll
        for (int r = 0; r < 4; r++) {
            float v = fmaxf(acc1[ct][r], 0.f);
            int row = w * 16 + q * 4 + r;
            hid[row * HSTRIDE + ct * 16 + m] = f2bf(v);
        }
    }
    f32x4 acc2[4];
#pragma unroll
    for (int ct = 0; ct < 4; ct++) {
        int col = ct * 16 + m;
        float bv = (col < HID) ? b2[col] : 0.f;
        acc2[ct] = (f32x4){bv, bv, bv, bv};
    }
#pragma unroll
    for (int ks = 0; ks < 4; ks++) {
        bf16x8 a = *(const bf16x8*)&hid[(w * 16 + m) * HSTRIDE + ks * 32 + q * 8];
#pragma unroll
        for (int ct = 0; ct < 4; ct++) {
            bf16x8 b = *(const bf16x8*)(w2f + ((size_t)(ct * 4 + ks) * 64 + lane) * 8);
            acc2[ct] = __builtin_amdgcn_mfma_f32_16x16x32_bf16(a, b, acc2[ct], 0, 0, 0);
        }
    }

    if (!LAST) {
#pragma unroll
        for (int ct = 0; ct < 4; ct++) {
#pragma unroll
            for (int r = 0; r < 4; r++) {
                int node = nb + q * 4 + r;
                if (node < n) {
                    float v = fmaxf(acc2[ct][r], 0.f);
                    hbout[(size_t)node * 64 + ct * 16 + m] = f2bf(v);
                }
            }
        }
    } else {
        // h3 (C-layout) -> LDS tile aliased onto zt: wave w's zt rows [w*16,w*16+16)
        // are fully consumed by the acc1 MFMAs above (same wave), so reuse is safe
        // without a barrier (wave-private rows in both roles).
        ushort_t* h3t = zt;
#pragma unroll
        for (int ct = 0; ct < 4; ct++) {
#pragma unroll
            for (int r = 0; r < 4; r++) {
                float v = fmaxf(acc2[ct][r], 0.f);
                h3t[(size_t)(w * 16 + q * 4 + r) * 68 + ct * 16 + m] = f2bf(v);
            }
        }
        // final: [16 x 256] @ [256 x 64]; segs x,h1,h2 from global, h3 from LDS
        f32x4 accF[4];
#pragma unroll
        for (int ct = 0; ct < 4; ct++) {
            int col = ct * 16 + m;
            float bv = (col < HID) ? lin_b[col] : 0.f;
            accF[ct] = (f32x4){bv, bv, bv, bv};
        }
        const ushort_t* segs[3] = {xb, h1b, h2b};
#pragma unroll
        for (int ks = 0; ks < 8; ks++) {
            bf16x8 a;
            if (ks < 6) {
                const ushort_t* p = segs[ks >> 1];
                a = *(const bf16x8*)(p + (size_t)anode * 64 + (ks & 1) * 32 + q * 8);
            } else {
                a = *(const bf16x8*)&h3t[(size_t)(w * 16 + m) * 68 + (ks & 1) * 32 + q * 8];
            }
#pragma unroll
            for (int ct = 0; ct < 4; ct++) {
                bf16x8 b = *(const bf16x8*)(linf + ((size_t)(ct * 8 + ks) * 64 + lane) * 8);
                accF[ct] = __builtin_amdgcn_mfma_f32_16x16x32_bf16(a, b, accF[ct], 0, 0, 0);
            }
        }
#pragma unroll
        for (int ct = 0; ct < 4; ct++) {
            int col = ct * 16 + m;
            if (col < HID) {
#pragma unroll
                for (int r = 0; r < 4; r++) {
                    int node = nb + q * 4 + r;
                    if (node < n)
                        out[(size_t)node * HID + col] = accF[ct][r];
                }
            }
        }
    }
}

extern "C" void kernel_launch(void* const* d_in, const int* in_sizes, int n_in,
                              void* d_out, int out_size, void* d_ws, size_t ws_size,
                              hipStream_t stream) {
    const float* x     = (const float*)d_in[0];
    const int*   ei    = (const int*)d_in[1];
    const float* w1    = (const float*)d_in[2];
    const float* b1    = (const float*)d_in[3];
    const float* w2    = (const float*)d_in[4];
    const float* b2    = (const float*)d_in[5];
    const float* eps   = (const float*)d_in[6];
    const float* lin_w = (const float*)d_in[7];
    const float* lin_b = (const float*)d_in[8];
    float* out = (float*)d_out;

    const int N = in_sizes[0] / HID;       // 100000
    const int E = in_sizes[1] / 2;         // 3200000
    const int* src = ei;
    const int* dst = ei + E;

    const int NBIN = (N + 255) / 256;      // 391

    // ---- workspace layout (16B-aligned blocks); gather tables have extra zero row N ----
    char* p = (char*)d_ws;
    const size_t ROWS = (size_t)(N + 1) * 64 * 2;
    ushort_t* xb  = (ushort_t*)p;  p += ROWS;
    ushort_t* h1b = (ushort_t*)p;  p += ROWS;
    ushort_t* h2b = (ushort_t*)p;  p += ROWS;
    ushort_t* w1f = (ushort_t*)p;  p += 3 * 14 * 512 * 2;
    ushort_t* w2f = (ushort_t*)p;  p += 3 * 16 * 512 * 2;
    ushort_t* linf= (ushort_t*)p;  p += 32 * 512 * 2;
    int* ghist    = (int*)p;       p += 512 * 4;
    int* gcnt     = (int*)p;       p += 512 * 4;     // contiguous with ghist for one memset
    int* binstart = (int*)p;       p += 512 * 4;
    int* nrs      = (int*)p;       p += (size_t)(N + 4) * 4;
    int* ndeg     = (int*)p;       p += (size_t)(N + 4) * 4;
    uint_t* packed = (uint_t*)p;   p += (size_t)E * 4;
    int* srcsorted = (int*)p;      // E + NBIN*4096 + 64 entries (prefetch slack)

    ushort_t* hbs[3] = {xb, h1b, h2b};

    const int BLK = 256;
    const int NP1 = (E + P1_CHUNK - 1) / P1_CHUNK;   // 391
    const int NXBLK = (N * 16 + BLK - 1) / BLK;      // 6250
    const int NBUCK = (N + 63) / 64;                 // 1563
    dim3 blk(BLK);

    // ---- setup (conv + bhist fused) then scan + 2-pass radix CSR build ----
    hipMemsetAsync(ghist, 0, 1024 * sizeof(int), stream);   // ghist + gcnt
    setup_kernel<<<NXBLK + 32 + NP1, blk, 0, stream>>>(x, w1, w2, lin_w, dst,
                                                       xb, h1b, h2b,
                                                       w1f, w2f, linf, ghist, N, E, NXBLK);
    binscan_kernel<<<1, blk, 0, stream>>>(ghist, binstart);
    pass1_kernel<<<NP1, blk, 0, stream>>>(src, dst, binstart, gcnt, packed, E);
    pass2_kernel<<<NBIN, blk, 0, stream>>>(packed, ghist, binstart, srcsorted, nrs, ndeg, N);

    // ---- layers 1,2 (fused agg+mlp) ----
    for (int l = 0; l < 2; l++) {
        aggmlp_kernel<0><<<NBUCK, blk, 0, stream>>>(hbs[l], nrs, ndeg, srcsorted, eps + l,
                                                    w1f + (size_t)l * 14 * 512,
                                                    b1 + (size_t)l * HID2,
                                                    w2f + (size_t)l * 16 * 512,
                                                    b2 + (size_t)l * HID,
                                                    hbs[l + 1],
                                                    nullptr, nullptr, nullptr,
                                                    nullptr, nullptr, nullptr, N);
    }
    // ---- layer 3 + fused final ----
    aggmlp_kernel<1><<<NBUCK, blk, 0, stream>>>(h2b, nrs, ndeg, srcsorted, eps + 2,
                                                w1f + 2 * 14 * 512,
                                                b1 + 2 * HID2,
                                                w2f + 2 * 16 * 512,
                                                b2 + 2 * HID,
                                                nullptr,
                                                xb, h1b, h2b,
                                                linf, lin_b, out, N);
}